// Round 4
// baseline (2030.246 us; speedup 1.0000x reference)
//
#include <hip/hip_runtime.h>
#include <stdint.h>

#define N_TOK   16384
#define DMODEL  1024
#define NEXP    8
#define DFF     4096
#define CAP     8192
#define MAXBLK  264          // 32768/128 + 8 (per-expert 128-row padding)
#define W_LOAD_C 0.01f

typedef __attribute__((ext_vector_type(8))) short short8;
typedef __attribute__((ext_vector_type(4))) float f32x4;

__device__ __forceinline__ uint16_t f2bf(float f) {
    uint32_t u = __float_as_uint(f);
    uint32_t r = u + 0x7fffu + ((u >> 16) & 1u);
    return (uint16_t)(r >> 16);
}

__device__ __forceinline__ float gelu_tanh(float v) {
    float u = 0.7978845608028654f * (v + 0.044715f * v * v * v);
    float ex = __expf(2.0f * u);
    float th = 1.0f - 2.0f / (ex + 1.0f);
    return 0.5f * v * (1.0f + th);
}

__device__ __forceinline__ void glds16(const uint16_t* g, uint16_t* l) {
    __builtin_amdgcn_global_load_lds(
        (const __attribute__((address_space(1))) void*)g,
        (__attribute__((address_space(3))) void*)l, 16, 0, 0);
}
// non-temporal (SLC) variant: aux bit1 — for streaming h reads in GEMM2
__device__ __forceinline__ void glds16nt(const uint16_t* g, uint16_t* l) {
    __builtin_amdgcn_global_load_lds(
        (const __attribute__((address_space(1))) void*)g,
        (__attribute__((address_space(3))) void*)l, 16, 0, 2);
}

// ---------------- gating + routing + load-loss + fused x->bf16 ----------------
// Dot-product code kept bitwise-identical to the passing rounds.
__global__ __launch_bounds__(512) void gating_kernel(
    const float* __restrict__ x, const float* __restrict__ noise,
    const float* __restrict__ gate_w, const float* __restrict__ noise_w,
    int* __restrict__ cnt, float* __restrict__ loadAcc,
    int* __restrict__ rowlist, float* __restrict__ slotw,
    uint16_t* __restrict__ xb)
{
    __shared__ float lp[8][8];
    __shared__ int   se1[8], se2[8];
    __shared__ float sw1[8], sw2[8];

    const int lane = threadIdx.x & 63;
    const int wid  = threadIdx.x >> 6;
    const int t = blockIdx.x * 8 + wid;

    const float* xr = x + (size_t)t * DMODEL;
    uint16_t* xbr = xb + (size_t)t * DMODEL;
    float ag[8] = {0,0,0,0,0,0,0,0};
    float an[8] = {0,0,0,0,0,0,0,0};
    for (int j = 0; j < 16; ++j) {
        int idx = j * 64 + lane;
        float xv = xr[idx];
        xbr[idx] = f2bf(xv);
        const float4* gp  = (const float4*)(gate_w  + idx * 8);
        const float4* np_ = (const float4*)(noise_w + idx * 8);
        float4 g0 = gp[0], g1 = gp[1];
        float4 n0 = np_[0], n1 = np_[1];
        ag[0] += xv * g0.x; ag[1] += xv * g0.y; ag[2] += xv * g0.z; ag[3] += xv * g0.w;
        ag[4] += xv * g1.x; ag[5] += xv * g1.y; ag[6] += xv * g1.z; ag[7] += xv * g1.w;
        an[0] += xv * n0.x; an[1] += xv * n0.y; an[2] += xv * n0.z; an[3] += xv * n0.w;
        an[4] += xv * n1.x; an[5] += xv * n1.y; an[6] += xv * n1.z; an[7] += xv * n1.w;
    }
    #pragma unroll
    for (int m = 32; m >= 1; m >>= 1) {
        #pragma unroll
        for (int e = 0; e < 8; ++e) {
            ag[e] += __shfl_xor(ag[e], m, 64);
            an[e] += __shfl_xor(an[e], m, 64);
        }
    }
    float logit[8], sdv[8];
    #pragma unroll
    for (int e = 0; e < 8; ++e) {
        float a = an[e];
        float sp = (a > 20.0f) ? a : log1pf(expf(a));
        sdv[e] = sp;
        logit[e] = ag[e] + noise[(size_t)t * 8 + e] * sp;
    }
    float v1 = -1e30f, v2 = -1e30f, v3 = -1e30f; int i1 = 0, i2 = 0;
    #pragma unroll
    for (int e = 0; e < 8; ++e) {
        float v = logit[e];
        if (v > v1)      { v3 = v2; v2 = v1; i2 = i1; v1 = v; i1 = e; }
        else if (v > v2) { v3 = v2; v2 = v; i2 = e; }
        else if (v > v3) { v3 = v; }
    }
    if (lane < 8) {
        float kth = (lane == i1 || lane == i2) ? v3 : v2;
        float z = (logit[lane] - kth) / sdv[lane];
        lp[wid][lane] = 0.5f * erfcf(-z * 0.70710678118654752440f);
    }
    if (lane == 0) {
        float e2 = expf(v2 - v1);
        float inv = 1.0f / (1.0f + e2);
        se1[wid] = i1; se2[wid] = i2;
        sw1[wid] = inv; sw2[wid] = e2 * inv;
    }
    __syncthreads();
    if (threadIdx.x < 8) {
        int e = threadIdx.x;
        float s = 0.f;
        #pragma unroll
        for (int w = 0; w < 8; ++w) s += lp[w][e];
        atomicAdd(&loadAcc[e], s);
        int m = 0;
        #pragma unroll
        for (int w = 0; w < 8; ++w) m += (se1[w] == e) + (se2[w] == e);
        if (m > 0) {
            int b = atomicAdd(&cnt[e], m);
            #pragma unroll
            for (int w = 0; w < 8; ++w) {
                int tok = blockIdx.x * 8 + w;
                if (se1[w] == e) {
                    if (b < CAP) { rowlist[e * CAP + b] = tok; slotw[e * CAP + b] = sw1[w]; }
                    b++;
                }
                if (se2[w] == e) {
                    if (b < CAP) { rowlist[e * CAP + b] = tok; slotw[e * CAP + b] = sw2[w]; }
                    b++;
                }
            }
        }
    }
}

// ---------------- block map scan ----------------
__global__ void scan_kernel(const int* __restrict__ cnt,
                            int* __restrict__ be, int* __restrict__ brow)
{
    if (threadIdx.x == 0 && blockIdx.x == 0) {
        int idx = 0;
        for (int e = 0; e < NEXP; ++e) {
            int ce = cnt[e]; if (ce > CAP) ce = CAP;
            int nb = (ce + 127) >> 7;
            for (int k = 0; k < nb; ++k) { be[idx] = e; brow[idx] = k * 128; idx++; }
        }
        for (; idx < MAXBLK; ++idx) { be[idx] = -1; brow[idx] = 0; }
    }
}

// ---------------- per-expert transpose f32 [R][C] -> bf16 [C][R] ----------------
__global__ __launch_bounds__(256) void transpose_w_kernel(
    const float* __restrict__ src, uint16_t* __restrict__ dst, int R, int Cc)
{
    __shared__ float tile[32][33];
    const float* s = src + (size_t)blockIdx.z * R * Cc;
    uint16_t*    d = dst + (size_t)blockIdx.z * R * Cc;
    int c0 = blockIdx.x * 32, r0 = blockIdx.y * 32;
    int tx = threadIdx.x & 31, ty = threadIdx.x >> 5;
    #pragma unroll
    for (int rr = ty; rr < 32; rr += 8)
        tile[rr][tx] = s[(size_t)(r0 + rr) * Cc + c0 + tx];
    __syncthreads();
    #pragma unroll
    for (int rr = ty; rr < 32; rr += 8)
        d[(size_t)(c0 + rr) * R + r0 + tx] = f2bf(tile[tx][rr]);
}

// ---------------- GEMM: 128x128 tile, BK=32, 4 waves, 2-phase LDS dbuf ----------------
// ANT: A loads non-temporal (streaming h in GEMM2).
// Non-ATOMIC epilogue: LDS-transposed, 16B-coalesced NON-TEMPORAL h stores
// (h must not allocate in L2/L3 — it is the stream that was thrashing them).
template<int KTOT, int GATHER, int GELU, int ATOMIC, int ANT>
__global__ __launch_bounds__(256) void gemm_kernel(
    const uint16_t* __restrict__ Abase,
    const uint16_t* __restrict__ Bfull,
    const int*      __restrict__ rowlist,
    const float*    __restrict__ slotw,
    const int*      __restrict__ cnt,
    const int*      __restrict__ be,
    const int*      __restrict__ brow,
    const float*    __restrict__ biasFull,
    uint16_t*       __restrict__ OutBf,
    float*          __restrict__ OutF,
    int ncols, int bo)
{
    // single 32KB arena: staging dbuf (A:2x8KB @0, B:2x8KB @16KB) during K-loop,
    // whole 128x128 u16 tile during the store epilogue.
    __shared__ uint16_t lsm[16384];
    __shared__ int   lT[128];
    __shared__ float lW[128];

    const int rb = blockIdx.y + bo;
    if (rb >= MAXBLK) return;
    const int e = be[rb];
    if (e < 0) return;
    const int row0 = brow[rb];
    int ce = cnt[e]; if (ce > CAP) ce = CAP;
    const int n0 = blockIdx.x * 128;

    const int t = threadIdx.x;
    const int lane = t & 63;
    const int wid = t >> 6;
    const int fr = lane & 15;
    const int ks = lane >> 4;

    if (GATHER || ATOMIC) {
        if (t < 128) {
            int r = row0 + t;
            int rc = (r < ce) ? r : (ce - 1);
            lT[t] = rowlist[e * CAP + rc];
            if (ATOMIC) lW[t] = (r < ce) ? slotw[e * CAP + r] : 0.0f;
        }
        __syncthreads();
    }

    const int ra0 = wid * 16 + fr;
    const int ra1 = 64 + wid * 16 + fr;
    size_t arow0, arow1;
    if (GATHER) { arow0 = (size_t)lT[ra0]; arow1 = (size_t)lT[ra1]; }
    else        { arow0 = (size_t)blockIdx.y * 128 + ra0;
                  arow1 = (size_t)blockIdx.y * 128 + ra1; }
    const uint16_t* pA0 = Abase + arow0 * KTOT + ks * 8;
    const uint16_t* pA1 = Abase + arow1 * KTOT + ks * 8;
    const uint16_t* Bp  = Bfull + (size_t)e * ncols * KTOT;
    const uint16_t* pB0 = Bp + (size_t)(n0 + ra0) * KTOT + ks * 8;
    const uint16_t* pB1 = Bp + (size_t)(n0 + ra1) * KTOT + ks * 8;

    f32x4 acc[4][4];
    #pragma unroll
    for (int a = 0; a < 4; ++a)
        #pragma unroll
        for (int b = 0; b < 4; ++b) acc[a][b] = (f32x4){0.f, 0.f, 0.f, 0.f};

    const int wr = wid >> 1, wc = wid & 1;
    constexpr int NT = KTOT / 32;

    // prologue: stage tile 0 into buffer 0
    if (ANT) { glds16nt(pA0, &lsm[t * 8]); glds16nt(pA1, &lsm[2048 + t * 8]); }
    else     { glds16  (pA0, &lsm[t * 8]); glds16  (pA1, &lsm[2048 + t * 8]); }
    glds16(pB0, &lsm[8192 + t * 8]);
    glds16(pB1, &lsm[8192 + 2048 + t * 8]);
    __syncthreads();

    for (int tk = 0; tk < NT; ++tk) {
        const int cur = tk & 1;
        if (tk + 1 < NT) {
            const int k1 = (tk + 1) * 32;
            const int nb = (cur ^ 1) * 4096;
            if (ANT) { glds16nt(pA0 + k1, &lsm[nb + t * 8]);
                       glds16nt(pA1 + k1, &lsm[nb + 2048 + t * 8]); }
            else     { glds16  (pA0 + k1, &lsm[nb + t * 8]);
                       glds16  (pA1 + k1, &lsm[nb + 2048 + t * 8]); }
            glds16(pB0 + k1, &lsm[8192 + nb + t * 8]);
            glds16(pB1 + k1, &lsm[8192 + nb + 2048 + t * 8]);
        }
        const int cb = cur * 4096;
        short8 af[4], bfr[4];
        #pragma unroll
        for (int mi = 0; mi < 4; ++mi)
            af[mi] = *(const short8*)&lsm[cb + (wr * 4 + mi) * 512 + lane * 8];
        #pragma unroll
        for (int ni = 0; ni < 4; ++ni)
            bfr[ni] = *(const short8*)&lsm[8192 + cb + (wc * 4 + ni) * 512 + lane * 8];
        #pragma unroll
        for (int mi = 0; mi < 4; ++mi)
            #pragma unroll
            for (int ni = 0; ni < 4; ++ni)
                acc[mi][ni] = __builtin_amdgcn_mfma_f32_16x16x32_bf16(
                    af[mi], bfr[ni], acc[mi][ni], 0, 0, 0);
        __syncthreads();
    }

    // epilogue: D mapping col = lane&15, row = (lane>>4)*4 + j  [m89/m91]
    const float* bias = biasFull + (size_t)e * ncols;
    if (ATOMIC) {
        const int colBase = n0 + wc * 64;
        #pragma unroll
        for (int mi = 0; mi < 4; ++mi) {
            int rloc = wr * 64 + mi * 16 + ks * 4;
            #pragma unroll
            for (int ni = 0; ni < 4; ++ni) {
                int c = colBase + ni * 16 + fr;
                float bv = bias[c];
                #pragma unroll
                for (int j = 0; j < 4; ++j) {
                    float v = acc[mi][ni][j] + bv;
                    int rl = rloc + j;
                    if (row0 + rl < ce)
                        atomicAdd(&OutF[(size_t)lT[rl] * DMODEL + c], lW[rl] * v);
                }
            }
        }
    } else {
        // stash tile in LDS (8-group XOR swizzle breaks bank conflicts), then
        // full-line 16B non-temporal stores.
        #pragma unroll
        for (int mi = 0; mi < 4; ++mi) {
            int rloc = wr * 64 + mi * 16 + ks * 4;
            #pragma unroll
            for (int ni = 0; ni < 4; ++ni) {
                int cl = wc * 64 + ni * 16 + fr;
                float bv = bias[n0 + cl];
                #pragma unroll
                for (int j = 0; j < 4; ++j) {
                    float v = acc[mi][ni][j] + bv;
                    if (GELU) v = gelu_tanh(v);
                    int rl = rloc + j;
                    lsm[rl * 128 + (cl ^ ((rl & 7) << 3))] = f2bf(v);
                }
            }
        }
        __syncthreads();
        const int r = t >> 1, half = t & 1;
        uint16_t* gp = OutBf + ((size_t)blockIdx.y * 128 + r) * ncols + n0 + half * 64;
        #pragma unroll
        for (int j2 = 0; j2 < 8; ++j2) {
            int cg = half * 64 + j2 * 8;
            short8 v = *(const short8*)&lsm[r * 128 + (cg ^ ((r & 7) << 3))];
            __builtin_nontemporal_store(v, (short8*)(gp + j2 * 8));
        }
    }
}

// ---------------- load-loss finalize ----------------
__global__ void finalize_kernel(const float* __restrict__ loadAcc, float* __restrict__ out) {
    if (threadIdx.x == 0) {
        float m = 0.f;
        #pragma unroll
        for (int e = 0; e < 8; ++e) m += loadAcc[e];
        m *= 0.125f;
        float v = 0.f;
        #pragma unroll
        for (int e = 0; e < 8; ++e) { float d0 = loadAcc[e] - m; v += d0 * d0; }
        v *= (1.0f / 7.0f);   // ddof=1
        out[(size_t)N_TOK * DMODEL] = W_LOAD_C * v / (m * m);
    }
}

extern "C" void kernel_launch(void* const* d_in, const int* in_sizes, int n_in,
                              void* d_out, int out_size, void* d_ws, size_t ws_size,
                              hipStream_t stream) {
    const float* x       = (const float*)d_in[0];
    const float* noise   = (const float*)d_in[1];
    const float* gate_w  = (const float*)d_in[2];
    const float* noise_w = (const float*)d_in[3];
    const float* w1      = (const float*)d_in[4];
    const float* b1      = (const float*)d_in[5];
    const float* w2      = (const float*)d_in[6];
    const float* b2      = (const float*)d_in[7];
    float* out = (float*)d_out;
    char* ws = (char*)d_ws;

    int*      cnt     = (int*)(ws + 0);
    float*    loadAcc = (float*)(ws + 256);
    int*      be      = (int*)(ws + 1024);
    int*      brow    = (int*)(ws + 3072);
    int*      rowlist = (int*)(ws + 8192);
    float*    slotw   = (float*)(ws + 270336);
    uint16_t* xb      = (uint16_t*)(ws + 532480);
    uint16_t* w1t     = (uint16_t*)(ws + 34086912);
    uint16_t* w2t     = (uint16_t*)(ws + 101195776);
    uint16_t* h       = (uint16_t*)(ws + 168304640);
    const size_t HOFF = 168304640ull;

    size_t avail = (ws_size > HOFF) ? ws_size - HOFF : 0;
    int nch = 8, bpc = (MAXBLK + 7) / 8;
    for (int c = 1; c <= 8; c <<= 1) {
        int b = (MAXBLK + c - 1) / c;
        if ((size_t)b * 128 * DFF * 2 <= avail) { nch = c; bpc = b; break; }
    }

    hipMemsetAsync(ws, 0, 8192, stream);
    hipMemsetAsync(d_out, 0, (size_t)out_size * sizeof(float), stream);

    gating_kernel<<<2048, 512, 0, stream>>>(x, noise, gate_w, noise_w,
                                            cnt, loadAcc, rowlist, slotw, xb);
    scan_kernel<<<1, 64, 0, stream>>>(cnt, be, brow);
    transpose_w_kernel<<<dim3(128, 32, 8), 256, 0, stream>>>(w1, w1t, 1024, 4096);
    transpose_w_kernel<<<dim3(32, 128, 8), 256, 0, stream>>>(w2, w2t, 4096, 1024);
    finalize_kernel<<<1, 64, 0, stream>>>(loadAcc, out);

    for (int c = 0; c < nch; ++c) {
        int bo = c * bpc;
        if (bo >= MAXBLK) break;
        gemm_kernel<1024, 1, 1, 0, 0><<<dim3(32, bpc), 256, 0, stream>>>(
            xb, w1t, rowlist, slotw, cnt, be, brow, b1, h, nullptr, DFF, bo);
        gemm_kernel<4096, 0, 0, 1, 1><<<dim3(8, bpc), 256, 0, stream>>>(
            h, w2t, rowlist, slotw, cnt, be, brow, b2, nullptr, out, DMODEL, bo);
    }
}

// Round 5
// 1344.951 us; speedup vs baseline: 1.5095x; 1.5095x over previous
//
#include <hip/hip_runtime.h>
#include <stdint.h>

#define N_TOK   16384
#define DMODEL  1024
#define NEXP    8
#define DFF     4096
#define CAP     8192
#define MAXB    136          // 32768/256 + 8 (per-expert 256-row padding)
#define W_LOAD_C 0.01f

typedef __attribute__((ext_vector_type(8))) short short8;
typedef __attribute__((ext_vector_type(4))) float f32x4;

__device__ __forceinline__ uint16_t f2bf(float f) {
    uint32_t u = __float_as_uint(f);
    uint32_t r = u + 0x7fffu + ((u >> 16) & 1u);
    return (uint16_t)(r >> 16);
}

__device__ __forceinline__ float gelu_tanh(float v) {
    float u = 0.7978845608028654f * (v + 0.044715f * v * v * v);
    float ex = __expf(2.0f * u);
    float th = 1.0f - 2.0f / (ex + 1.0f);
    return 0.5f * v * (1.0f + th);
}

__device__ __forceinline__ void glds16(const uint16_t* g, uint16_t* l) {
    __builtin_amdgcn_global_load_lds(
        (const __attribute__((address_space(1))) void*)g,
        (__attribute__((address_space(3))) void*)l, 16, 0, 0);
}

// ---------------- gating + routing + load-loss + fused x->bf16 ----------------
// Dot-product code kept bitwise-identical to the passing rounds.
__global__ __launch_bounds__(512) void gating_kernel(
    const float* __restrict__ x, const float* __restrict__ noise,
    const float* __restrict__ gate_w, const float* __restrict__ noise_w,
    int* __restrict__ cnt, float* __restrict__ loadAcc,
    int* __restrict__ rowlist, float* __restrict__ slotw,
    uint16_t* __restrict__ xb)
{
    __shared__ float lp[8][8];
    __shared__ int   se1[8], se2[8];
    __shared__ float sw1[8], sw2[8];

    const int lane = threadIdx.x & 63;
    const int wid  = threadIdx.x >> 6;
    const int t = blockIdx.x * 8 + wid;

    const float* xr = x + (size_t)t * DMODEL;
    uint16_t* xbr = xb + (size_t)t * DMODEL;
    float ag[8] = {0,0,0,0,0,0,0,0};
    float an[8] = {0,0,0,0,0,0,0,0};
    for (int j = 0; j < 16; ++j) {
        int idx = j * 64 + lane;
        float xv = xr[idx];
        xbr[idx] = f2bf(xv);
        const float4* gp  = (const float4*)(gate_w  + idx * 8);
        const float4* np_ = (const float4*)(noise_w + idx * 8);
        float4 g0 = gp[0], g1 = gp[1];
        float4 n0 = np_[0], n1 = np_[1];
        ag[0] += xv * g0.x; ag[1] += xv * g0.y; ag[2] += xv * g0.z; ag[3] += xv * g0.w;
        ag[4] += xv * g1.x; ag[5] += xv * g1.y; ag[6] += xv * g1.z; ag[7] += xv * g1.w;
        an[0] += xv * n0.x; an[1] += xv * n0.y; an[2] += xv * n0.z; an[3] += xv * n0.w;
        an[4] += xv * n1.x; an[5] += xv * n1.y; an[6] += xv * n1.z; an[7] += xv * n1.w;
    }
    #pragma unroll
    for (int m = 32; m >= 1; m >>= 1) {
        #pragma unroll
        for (int e = 0; e < 8; ++e) {
            ag[e] += __shfl_xor(ag[e], m, 64);
            an[e] += __shfl_xor(an[e], m, 64);
        }
    }
    float logit[8], sdv[8];
    #pragma unroll
    for (int e = 0; e < 8; ++e) {
        float a = an[e];
        float sp = (a > 20.0f) ? a : log1pf(expf(a));
        sdv[e] = sp;
        logit[e] = ag[e] + noise[(size_t)t * 8 + e] * sp;
    }
    float v1 = -1e30f, v2 = -1e30f, v3 = -1e30f; int i1 = 0, i2 = 0;
    #pragma unroll
    for (int e = 0; e < 8; ++e) {
        float v = logit[e];
        if (v > v1)      { v3 = v2; v2 = v1; i2 = i1; v1 = v; i1 = e; }
        else if (v > v2) { v3 = v2; v2 = v; i2 = e; }
        else if (v > v3) { v3 = v; }
    }
    if (lane < 8) {
        float kth = (lane == i1 || lane == i2) ? v3 : v2;
        float z = (logit[lane] - kth) / sdv[lane];
        lp[wid][lane] = 0.5f * erfcf(-z * 0.70710678118654752440f);
    }
    if (lane == 0) {
        float e2 = expf(v2 - v1);
        float inv = 1.0f / (1.0f + e2);
        se1[wid] = i1; se2[wid] = i2;
        sw1[wid] = inv; sw2[wid] = e2 * inv;
    }
    __syncthreads();
    if (threadIdx.x < 8) {
        int e = threadIdx.x;
        float s = 0.f;
        #pragma unroll
        for (int w = 0; w < 8; ++w) s += lp[w][e];
        atomicAdd(&loadAcc[e], s);
        int m = 0;
        #pragma unroll
        for (int w = 0; w < 8; ++w) m += (se1[w] == e) + (se2[w] == e);
        if (m > 0) {
            int b = atomicAdd(&cnt[e], m);
            #pragma unroll
            for (int w = 0; w < 8; ++w) {
                int tok = blockIdx.x * 8 + w;
                if (se1[w] == e) {
                    if (b < CAP) { rowlist[e * CAP + b] = tok; slotw[e * CAP + b] = sw1[w]; }
                    b++;
                }
                if (se2[w] == e) {
                    if (b < CAP) { rowlist[e * CAP + b] = tok; slotw[e * CAP + b] = sw2[w]; }
                    b++;
                }
            }
        }
    }
}

// ---------------- block map scan: expert/row per 256-row packed block ----------------
__global__ void scan_kernel(const int* __restrict__ cnt,
                            int* __restrict__ be, int* __restrict__ brow)
{
    if (threadIdx.x == 0 && blockIdx.x == 0) {
        int idx = 0;
        for (int e = 0; e < NEXP; ++e) {
            int ce = cnt[e]; if (ce > CAP) ce = CAP;
            int nb = (ce + 255) >> 8;
            for (int k = 0; k < nb; ++k) { be[idx] = e; brow[idx] = k * 256; idx++; }
        }
        for (; idx < MAXB; ++idx) { be[idx] = -1; brow[idx] = 0; }
    }
}

// ---------------- per-expert transpose f32 [R][C] -> bf16 [C][R] ----------------
__global__ __launch_bounds__(256) void transpose_w_kernel(
    const float* __restrict__ src, uint16_t* __restrict__ dst, int R, int Cc)
{
    __shared__ float tile[32][33];
    const float* s = src + (size_t)blockIdx.z * R * Cc;
    uint16_t*    d = dst + (size_t)blockIdx.z * R * Cc;
    int c0 = blockIdx.x * 32, r0 = blockIdx.y * 32;
    int tx = threadIdx.x & 31, ty = threadIdx.x >> 5;
    #pragma unroll
    for (int rr = ty; rr < 32; rr += 8)
        tile[rr][tx] = s[(size_t)(r0 + rr) * Cc + c0 + tx];
    __syncthreads();
    #pragma unroll
    for (int rr = ty; rr < 32; rr += 8)
        d[(size_t)(c0 + rr) * R + r0 + tx] = f2bf(tile[tx][rr]);
}

// ---------------- GEMM: 256x256 tile, BK=32, 8 waves, 4-deep ring + counted vmcnt ----
// T3+T4: stage kt+3 while computing kt; s_waitcnt vmcnt(8) (never 0 in loop) +
// RAW s_barrier (no compiler vmcnt(0) drain). T2: XOR-swizzle, both sides
// (pre-swizzled per-lane global source + swizzled ds_read). T5: setprio.
// T1: bijective XCD swizzle (m204) so a row-block's column panels share an XCD L2.
template<int KTOT, int GATHER, int GELU, int ATOMIC>
__global__ __launch_bounds__(512, 2) void gemm_kernel(
    const uint16_t* __restrict__ Abase,
    const uint16_t* __restrict__ Bfull,
    const int*      __restrict__ rowlist,
    const float*    __restrict__ slotw,
    const int*      __restrict__ cnt,
    const int*      __restrict__ be,
    const int*      __restrict__ brow,
    const float*    __restrict__ biasFull,
    uint16_t*       __restrict__ OutBf,
    float*          __restrict__ OutF,
    int ncols, int bo)
{
    __shared__ uint16_t lsm[65536];  // 128 KiB: 4 bufs x (A 8192 + B 8192 elems)
    __shared__ int   lT[256];
    __shared__ float lW[256];

    // bijective XCD swizzle (m204): consecutive f2 share an XCD
    const int nwg  = gridDim.x * gridDim.y;
    const int flat = blockIdx.y * gridDim.x + blockIdx.x;
    const int xcd = flat & 7, sid = flat >> 3;
    const int q = nwg >> 3, r8 = nwg & 7;
    const int f2 = (xcd < r8 ? xcd * (q + 1) : r8 * (q + 1) + (xcd - r8) * q) + sid;
    const int nx  = f2 % gridDim.x;   // column panel (fast within an XCD)
    const int rbi = f2 / gridDim.x;   // row-block (grid-local)

    const int rb = rbi + bo;
    if (rb >= MAXB) return;
    const int e = be[rb];
    if (e < 0) return;
    const int row0 = brow[rb];
    int ce = cnt[e]; if (ce > CAP) ce = CAP;
    const int n0 = nx * 256;

    const int t = threadIdx.x;
    const int lane = t & 63;
    const int wid  = t >> 6;            // 0..7
    const int fr = lane & 15, ks = lane >> 4;
    const int wr = wid >> 2, wc = wid & 3;   // 2(M) x 4(N) wave grid

    if (ATOMIC) {
        if (t < 256) {
            int rr = row0 + t;
            int rc = (rr < ce) ? rr : (ce - 1);
            lT[t] = rowlist[e * CAP + rc];
            lW[t] = (rr < ce) ? slotw[e * CAP + rr] : 0.0f;
        }
    }
    __syncthreads();

    // ---- staging pointers (fixed per thread across K-tiles) ----
    // instr = wid + 8*i covers 16 rows/cols; lane covers row instr*16+(l>>2),
    // granule slot l&3; source granule pre-swizzled: s = slot ^ (r&3) ^ ((r>>2)&3)
    const uint16_t* Bp = Bfull + (size_t)e * ncols * KTOT;
    const uint16_t* aSrc[2];
    const uint16_t* bSrc[2];
    int dstA[2], dstB[2];
    #pragma unroll
    for (int i = 0; i < 2; ++i) {
        const int instr = wid + 8 * i;
        const int r = instr * 16 + (lane >> 2);
        const int s = (lane & 3) ^ (r & 3) ^ ((r >> 2) & 3);
        size_t grow;
        if (GATHER) {
            int rr = row0 + r;
            grow = (size_t)rowlist[e * CAP + ((rr < ce) ? rr : (ce - 1))];
        } else {
            grow = (size_t)rbi * 256 + r;
        }
        aSrc[i] = Abase + grow * KTOT + s * 8;
        dstA[i] = instr * 512 + lane * 8;
        const int sb = s;                 // same formula, c == r numerically
        bSrc[i] = Bp + (size_t)(n0 + r) * KTOT + sb * 8;
        dstB[i] = 8192 + instr * 512 + lane * 8;
    }

    // ---- fragment ds_read offsets (swizzled; fixed per thread) ----
    int offA[8], offB[4];
    #pragma unroll
    for (int g = 0; g < 8; ++g) {
        int r = wr * 128 + g * 16 + fr;
        offA[g] = r * 32 + ((ks ^ (r & 3) ^ ((r >> 2) & 3)) * 8);
    }
    #pragma unroll
    for (int n = 0; n < 4; ++n) {
        int c = wc * 64 + n * 16 + fr;
        offB[n] = 8192 + c * 32 + ((ks ^ (c & 3) ^ ((c >> 2) & 3)) * 8);
    }

    f32x4 acc[8][4];
    #pragma unroll
    for (int a = 0; a < 8; ++a)
        #pragma unroll
        for (int b = 0; b < 4; ++b) acc[a][b] = (f32x4){0.f, 0.f, 0.f, 0.f};

    constexpr int NKT = KTOT / 32;   // >= 32

    // prologue: stage kt = 0,1,2 into bufs 0,1,2 (12 instrs/thread-wave path)
    #pragma unroll
    for (int p = 0; p < 3; ++p) {
        const int ko = p * 32;
        const int bb = p * 16384;
        glds16(aSrc[0] + ko, &lsm[bb + dstA[0]]);
        glds16(aSrc[1] + ko, &lsm[bb + dstA[1]]);
        glds16(bSrc[0] + ko, &lsm[bb + dstB[0]]);
        glds16(bSrc[1] + ko, &lsm[bb + dstB[1]]);
    }
    asm volatile("s_waitcnt vmcnt(8)" ::: "memory");   // kt0 complete
    __builtin_amdgcn_s_barrier();
    asm volatile("" ::: "memory");

    for (int kt = 0; kt < NKT; ++kt) {
        const int b = kt & 3;
        if (kt + 3 < NKT) {            // stage 3 tiles ahead into the free buf
            const int ko = (kt + 3) * 32;
            const int bb = ((kt + 3) & 3) * 16384;
            glds16(aSrc[0] + ko, &lsm[bb + dstA[0]]);
            glds16(aSrc[1] + ko, &lsm[bb + dstA[1]]);
            glds16(bSrc[0] + ko, &lsm[bb + dstB[0]]);
            glds16(bSrc[1] + ko, &lsm[bb + dstB[1]]);
        }
        const uint16_t* ab = &lsm[b * 16384];
        short8 af[8], bf[4];
        #pragma unroll
        for (int g = 0; g < 8; ++g) af[g] = *(const short8*)(ab + offA[g]);
        #pragma unroll
        for (int n = 0; n < 4; ++n) bf[n] = *(const short8*)(ab + offB[n]);
        __builtin_amdgcn_s_setprio(1);
        #pragma unroll
        for (int mi = 0; mi < 8; ++mi)
            #pragma unroll
            for (int ni = 0; ni < 4; ++ni)
                acc[mi][ni] = __builtin_amdgcn_mfma_f32_16x16x32_bf16(
                    af[mi], bf[ni], acc[mi][ni], 0, 0, 0);
        __builtin_amdgcn_s_setprio(0);
        // counted wait: next tile's 4 loads complete; 8 newest stay in flight
        const int nin = NKT - 1 - kt;
        if (nin >= 3)      asm volatile("s_waitcnt vmcnt(8)" ::: "memory");
        else if (nin == 2) asm volatile("s_waitcnt vmcnt(4)" ::: "memory");
        else if (nin == 1) asm volatile("s_waitcnt vmcnt(0)" ::: "memory");
        __builtin_amdgcn_s_barrier();
        asm volatile("" ::: "memory");
    }

    // ---- epilogue: D mapping col = lane&15, row = (lane>>4)*4 + j [m89/m91] ----
    const float* bias = biasFull + (size_t)e * ncols;
    if (ATOMIC) {
        #pragma unroll
        for (int mi = 0; mi < 8; ++mi) {
            const int rbase = wr * 128 + mi * 16 + ks * 4;
            #pragma unroll
            for (int ni = 0; ni < 4; ++ni) {
                const int c = n0 + wc * 64 + ni * 16 + fr;
                const float bv = bias[c];
                #pragma unroll
                for (int j = 0; j < 4; ++j) {
                    const int rl = rbase + j;
                    if (row0 + rl < ce) {
                        float v = acc[mi][ni][j] + bv;
                        atomicAdd(&OutF[(size_t)lT[rl] * DMODEL + c], lW[rl] * v);
                    }
                }
            }
        }
    } else {
        // staged, coalesced h stores; two 128-row halves through the LDS arena
        for (int half = 0; half < 2; ++half) {
            __syncthreads();
            if (wr == half) {
                #pragma unroll
                for (int mi = 0; mi < 8; ++mi) {
                    #pragma unroll
                    for (int ni = 0; ni < 4; ++ni) {
                        const int cl = wc * 64 + ni * 16 + fr;
                        const float bv = bias[n0 + cl];
                        #pragma unroll
                        for (int j = 0; j < 4; ++j) {
                            float v = acc[mi][ni][j] + bv;
                            if (GELU) v = gelu_tanh(v);
                            const int rl2 = mi * 16 + ks * 4 + j;
                            lsm[rl2 * 264 + cl] = f2bf(v);   // stride 264: 2-way max
                        }
                    }
                }
            }
            __syncthreads();
            #pragma unroll
            for (int p = 0; p < 8; ++p) {
                const int r2 = p * 16 + (t >> 5);
                const int cg = (t & 31) * 8;
                short8 v = *(const short8*)&lsm[r2 * 264 + cg];
                *(short8*)&OutBf[((size_t)rbi * 256 + half * 128 + r2) * ncols + n0 + cg] = v;
            }
        }
    }
}

// ---------------- load-loss finalize ----------------
__global__ void finalize_kernel(const float* __restrict__ loadAcc, float* __restrict__ out) {
    if (threadIdx.x == 0) {
        float m = 0.f;
        #pragma unroll
        for (int e = 0; e < 8; ++e) m += loadAcc[e];
        m *= 0.125f;
        float v = 0.f;
        #pragma unroll
        for (int e = 0; e < 8; ++e) { float d0 = loadAcc[e] - m; v += d0 * d0; }
        v *= (1.0f / 7.0f);   // ddof=1
        out[(size_t)N_TOK * DMODEL] = W_LOAD_C * v / (m * m);
    }
}

extern "C" void kernel_launch(void* const* d_in, const int* in_sizes, int n_in,
                              void* d_out, int out_size, void* d_ws, size_t ws_size,
                              hipStream_t stream) {
    const float* x       = (const float*)d_in[0];
    const float* noise   = (const float*)d_in[1];
    const float* gate_w  = (const float*)d_in[2];
    const float* noise_w = (const float*)d_in[3];
    const float* w1      = (const float*)d_in[4];
    const float* b1      = (const float*)d_in[5];
    const float* w2      = (const float*)d_in[6];
    const float* b2      = (const float*)d_in[7];
    float* out = (float*)d_out;
    char* ws = (char*)d_ws;

    int*      cnt     = (int*)(ws + 0);
    float*    loadAcc = (float*)(ws + 256);
    int*      be      = (int*)(ws + 1024);
    int*      brow    = (int*)(ws + 3072);
    int*      rowlist = (int*)(ws + 8192);
    float*    slotw   = (float*)(ws + 270336);
    uint16_t* xb      = (uint16_t*)(ws + 532480);
    uint16_t* w1t     = (uint16_t*)(ws + 34086912);
    uint16_t* w2t     = (uint16_t*)(ws + 101195776);
    uint16_t* h       = (uint16_t*)(ws + 168304640);
    const size_t HOFF = 168304640ull;

    // chunking: h per 256-row block = 2 MB
    size_t avail = (ws_size > HOFF) ? ws_size - HOFF : 0;
    int nch = 8, bpc = (MAXB + 7) / 8;
    for (int c = 1; c <= 8; c <<= 1) {
        int b = (MAXB + c - 1) / c;
        if ((size_t)b * 256 * DFF * 2 <= avail) { nch = c; bpc = b; break; }
    }

    hipMemsetAsync(ws, 0, 8192, stream);
    hipMemsetAsync(d_out, 0, (size_t)out_size * sizeof(float), stream);

    gating_kernel<<<2048, 512, 0, stream>>>(x, noise, gate_w, noise_w,
                                            cnt, loadAcc, rowlist, slotw, xb);
    scan_kernel<<<1, 64, 0, stream>>>(cnt, be, brow);
    transpose_w_kernel<<<dim3(128, 32, 8), 256, 0, stream>>>(w1, w1t, 1024, 4096);
    transpose_w_kernel<<<dim3(32, 128, 8), 256, 0, stream>>>(w2, w2t, 4096, 1024);
    finalize_kernel<<<1, 64, 0, stream>>>(loadAcc, out);

    for (int c = 0; c < nch; ++c) {
        int bo = c * bpc;
        if (bo >= MAXB) break;
        gemm_kernel<1024, 1, 1, 0><<<dim3(16, bpc), 512, 0, stream>>>(
            xb, w1t, rowlist, slotw, cnt, be, brow, b1, h, nullptr, DFF, bo);
        gemm_kernel<4096, 0, 0, 1><<<dim3(4, bpc), 512, 0, stream>>>(
            h, w2t, rowlist, slotw, cnt, be, brow, b2, nullptr, out, DMODEL, bo);
    }
}

// Round 6
// 1068.503 us; speedup vs baseline: 1.9001x; 1.2587x over previous
//
#include <hip/hip_runtime.h>
#include <stdint.h>

#define N_TOK   16384
#define DMODEL  1024
#define NEXP    8
#define DFF     4096
#define CAP     8192
#define MAXB    136          // 32768/256 + 8 (per-expert 256-row padding)
#define W_LOAD_C 0.01f

typedef __attribute__((ext_vector_type(8))) short short8;
typedef __attribute__((ext_vector_type(4))) float f32x4;

__device__ __forceinline__ uint16_t f2bf(float f) {
    uint32_t u = __float_as_uint(f);
    uint32_t r = u + 0x7fffu + ((u >> 16) & 1u);
    return (uint16_t)(r >> 16);
}
__device__ __forceinline__ float bf2f(uint16_t u) {
    return __uint_as_float((uint32_t)u << 16);
}

__device__ __forceinline__ float gelu_tanh(float v) {
    float u = 0.7978845608028654f * (v + 0.044715f * v * v * v);
    float ex = __expf(2.0f * u);
    float th = 1.0f - 2.0f / (ex + 1.0f);
    return 0.5f * v * (1.0f + th);
}

__device__ __forceinline__ void glds16(const uint16_t* g, uint16_t* l) {
    __builtin_amdgcn_global_load_lds(
        (const __attribute__((address_space(1))) void*)g,
        (__attribute__((address_space(3))) void*)l, 16, 0, 0);
}

// ---------------- gating + routing + load-loss + fused x->bf16 ----------------
// Dot-product code kept bitwise-identical to the passing rounds.
// NEW: records per-token pair positions (tpos = e*32768 + slot) and weights.
__global__ __launch_bounds__(512) void gating_kernel(
    const float* __restrict__ x, const float* __restrict__ noise,
    const float* __restrict__ gate_w, const float* __restrict__ noise_w,
    int* __restrict__ cnt, float* __restrict__ loadAcc,
    int* __restrict__ rowlist, float* __restrict__ slotw,
    int* __restrict__ tpos0, int* __restrict__ tpos1,
    float* __restrict__ tw0, float* __restrict__ tw1,
    uint16_t* __restrict__ xb)
{
    __shared__ float lp[8][8];
    __shared__ int   se1[8], se2[8];
    __shared__ float sw1[8], sw2[8];

    const int lane = threadIdx.x & 63;
    const int wid  = threadIdx.x >> 6;
    const int t = blockIdx.x * 8 + wid;

    const float* xr = x + (size_t)t * DMODEL;
    uint16_t* xbr = xb + (size_t)t * DMODEL;
    float ag[8] = {0,0,0,0,0,0,0,0};
    float an[8] = {0,0,0,0,0,0,0,0};
    for (int j = 0; j < 16; ++j) {
        int idx = j * 64 + lane;
        float xv = xr[idx];
        xbr[idx] = f2bf(xv);
        const float4* gp  = (const float4*)(gate_w  + idx * 8);
        const float4* np_ = (const float4*)(noise_w + idx * 8);
        float4 g0 = gp[0], g1 = gp[1];
        float4 n0 = np_[0], n1 = np_[1];
        ag[0] += xv * g0.x; ag[1] += xv * g0.y; ag[2] += xv * g0.z; ag[3] += xv * g0.w;
        ag[4] += xv * g1.x; ag[5] += xv * g1.y; ag[6] += xv * g1.z; ag[7] += xv * g1.w;
        an[0] += xv * n0.x; an[1] += xv * n0.y; an[2] += xv * n0.z; an[3] += xv * n0.w;
        an[4] += xv * n1.x; an[5] += xv * n1.y; an[6] += xv * n1.z; an[7] += xv * n1.w;
    }
    #pragma unroll
    for (int m = 32; m >= 1; m >>= 1) {
        #pragma unroll
        for (int e = 0; e < 8; ++e) {
            ag[e] += __shfl_xor(ag[e], m, 64);
            an[e] += __shfl_xor(an[e], m, 64);
        }
    }
    float logit[8], sdv[8];
    #pragma unroll
    for (int e = 0; e < 8; ++e) {
        float a = an[e];
        float sp = (a > 20.0f) ? a : log1pf(expf(a));
        sdv[e] = sp;
        logit[e] = ag[e] + noise[(size_t)t * 8 + e] * sp;
    }
    float v1 = -1e30f, v2 = -1e30f, v3 = -1e30f; int i1 = 0, i2 = 0;
    #pragma unroll
    for (int e = 0; e < 8; ++e) {
        float v = logit[e];
        if (v > v1)      { v3 = v2; v2 = v1; i2 = i1; v1 = v; i1 = e; }
        else if (v > v2) { v3 = v2; v2 = v; i2 = e; }
        else if (v > v3) { v3 = v; }
    }
    if (lane < 8) {
        float kth = (lane == i1 || lane == i2) ? v3 : v2;
        float z = (logit[lane] - kth) / sdv[lane];
        lp[wid][lane] = 0.5f * erfcf(-z * 0.70710678118654752440f);
    }
    if (lane == 0) {
        float e2 = expf(v2 - v1);
        float inv = 1.0f / (1.0f + e2);
        se1[wid] = i1; se2[wid] = i2;
        sw1[wid] = inv; sw2[wid] = e2 * inv;
        tw0[t] = inv; tw1[t] = e2 * inv;
    }
    __syncthreads();
    if (threadIdx.x < 8) {
        int e = threadIdx.x;
        float s = 0.f;
        #pragma unroll
        for (int w = 0; w < 8; ++w) s += lp[w][e];
        atomicAdd(&loadAcc[e], s);
        int m = 0;
        #pragma unroll
        for (int w = 0; w < 8; ++w) m += (se1[w] == e) + (se2[w] == e);
        if (m > 0) {
            int b = atomicAdd(&cnt[e], m);
            #pragma unroll
            for (int w = 0; w < 8; ++w) {
                int tok = blockIdx.x * 8 + w;
                if (se1[w] == e) {
                    if (b < CAP) { rowlist[e * CAP + b] = tok; slotw[e * CAP + b] = sw1[w]; }
                    tpos0[tok] = e * 32768 + b;
                    b++;
                }
                if (se2[w] == e) {
                    if (b < CAP) { rowlist[e * CAP + b] = tok; slotw[e * CAP + b] = sw2[w]; }
                    tpos1[tok] = e * 32768 + b;
                    b++;
                }
            }
        }
    }
}

// ---------------- block map scan: expert/row per 256-row packed block ----------------
__global__ void scan_kernel(const int* __restrict__ cnt,
                            int* __restrict__ be, int* __restrict__ brow,
                            int* __restrict__ ebase)
{
    if (threadIdx.x == 0 && blockIdx.x == 0) {
        int idx = 0;
        for (int e = 0; e < NEXP; ++e) {
            int ce = cnt[e]; if (ce > CAP) ce = CAP;
            int nb = (ce + 255) >> 8;
            ebase[e] = idx * 256;   // packed base row of expert e
            for (int k = 0; k < nb; ++k) { be[idx] = e; brow[idx] = k * 256; idx++; }
        }
        for (; idx < MAXB; ++idx) { be[idx] = -1; brow[idx] = 0; }
    }
}

// ---------------- per-expert transpose f32 [R][C] -> bf16 [C][R] ----------------
__global__ __launch_bounds__(256) void transpose_w_kernel(
    const float* __restrict__ src, uint16_t* __restrict__ dst, int R, int Cc)
{
    __shared__ float tile[32][33];
    const float* s = src + (size_t)blockIdx.z * R * Cc;
    uint16_t*    d = dst + (size_t)blockIdx.z * R * Cc;
    int c0 = blockIdx.x * 32, r0 = blockIdx.y * 32;
    int tx = threadIdx.x & 31, ty = threadIdx.x >> 5;
    #pragma unroll
    for (int rr = ty; rr < 32; rr += 8)
        tile[rr][tx] = s[(size_t)(r0 + rr) * Cc + c0 + tx];
    __syncthreads();
    #pragma unroll
    for (int rr = ty; rr < 32; rr += 8)
        d[(size_t)(c0 + rr) * R + r0 + tx] = f2bf(tile[tx][rr]);
}

// ---------------- GEMM: 256x256 tile, BK=32, 8 waves, 4-deep ring + counted vmcnt ----
// Unchanged core from round 5 (T1 bijective XCD swizzle, T2 both-sides granule
// swizzle, T3/T4 ring + counted vmcnt, T5 setprio). Non-ATOMIC epilogue now
// used by BOTH GEMMs (GEMM2 stores y+b2 bf16 into packed y2; combine gathers).
template<int KTOT, int GATHER, int GELU, int ATOMIC>
__global__ __launch_bounds__(512, 2) void gemm_kernel(
    const uint16_t* __restrict__ Abase,
    const uint16_t* __restrict__ Bfull,
    const int*      __restrict__ rowlist,
    const float*    __restrict__ slotw,
    const int*      __restrict__ cnt,
    const int*      __restrict__ be,
    const int*      __restrict__ brow,
    const float*    __restrict__ biasFull,
    uint16_t*       __restrict__ OutBf,
    float*          __restrict__ OutF,
    int ncols, int bo)
{
    __shared__ uint16_t lsm[65536];  // 128 KiB: 4 bufs x (A 8192 + B 8192 elems)
    __shared__ int   lT[256];
    __shared__ float lW[256];

    // bijective XCD swizzle (m204)
    const int nwg  = gridDim.x * gridDim.y;
    const int flat = blockIdx.y * gridDim.x + blockIdx.x;
    const int xcd = flat & 7, sid = flat >> 3;
    const int q = nwg >> 3, r8 = nwg & 7;
    const int f2 = (xcd < r8 ? xcd * (q + 1) : r8 * (q + 1) + (xcd - r8) * q) + sid;
    const int nx  = f2 % gridDim.x;
    const int rbi = f2 / gridDim.x;

    const int rb = rbi + bo;
    if (rb >= MAXB) return;
    const int e = be[rb];
    if (e < 0) return;
    const int row0 = brow[rb];
    int ce = cnt[e]; if (ce > CAP) ce = CAP;
    const int n0 = nx * 256;

    const int t = threadIdx.x;
    const int lane = t & 63;
    const int wid  = t >> 6;
    const int fr = lane & 15, ks = lane >> 4;
    const int wr = wid >> 2, wc = wid & 3;

    if (ATOMIC) {
        if (t < 256) {
            int rr = row0 + t;
            int rc = (rr < ce) ? rr : (ce - 1);
            lT[t] = rowlist[e * CAP + rc];
            lW[t] = (rr < ce) ? slotw[e * CAP + rr] : 0.0f;
        }
    }
    __syncthreads();

    const uint16_t* Bp = Bfull + (size_t)e * ncols * KTOT;
    const uint16_t* aSrc[2];
    const uint16_t* bSrc[2];
    int dstA[2], dstB[2];
    #pragma unroll
    for (int i = 0; i < 2; ++i) {
        const int instr = wid + 8 * i;
        const int r = instr * 16 + (lane >> 2);
        const int s = (lane & 3) ^ (r & 3) ^ ((r >> 2) & 3);
        size_t grow;
        if (GATHER) {
            int rr = row0 + r;
            grow = (size_t)rowlist[e * CAP + ((rr < ce) ? rr : (ce - 1))];
        } else {
            grow = (size_t)rbi * 256 + r;
        }
        aSrc[i] = Abase + grow * KTOT + s * 8;
        dstA[i] = instr * 512 + lane * 8;
        bSrc[i] = Bp + (size_t)(n0 + r) * KTOT + s * 8;
        dstB[i] = 8192 + instr * 512 + lane * 8;
    }

    int offA[8], offB[4];
    #pragma unroll
    for (int g = 0; g < 8; ++g) {
        int r = wr * 128 + g * 16 + fr;
        offA[g] = r * 32 + ((ks ^ (r & 3) ^ ((r >> 2) & 3)) * 8);
    }
    #pragma unroll
    for (int n = 0; n < 4; ++n) {
        int c = wc * 64 + n * 16 + fr;
        offB[n] = 8192 + c * 32 + ((ks ^ (c & 3) ^ ((c >> 2) & 3)) * 8);
    }

    f32x4 acc[8][4];
    #pragma unroll
    for (int a = 0; a < 8; ++a)
        #pragma unroll
        for (int b = 0; b < 4; ++b) acc[a][b] = (f32x4){0.f, 0.f, 0.f, 0.f};

    constexpr int NKT = KTOT / 32;

    #pragma unroll
    for (int p = 0; p < 3; ++p) {
        const int ko = p * 32;
        const int bb = p * 16384;
        glds16(aSrc[0] + ko, &lsm[bb + dstA[0]]);
        glds16(aSrc[1] + ko, &lsm[bb + dstA[1]]);
        glds16(bSrc[0] + ko, &lsm[bb + dstB[0]]);
        glds16(bSrc[1] + ko, &lsm[bb + dstB[1]]);
    }
    asm volatile("s_waitcnt vmcnt(8)" ::: "memory");
    __builtin_amdgcn_s_barrier();
    asm volatile("" ::: "memory");

    for (int kt = 0; kt < NKT; ++kt) {
        const int b = kt & 3;
        if (kt + 3 < NKT) {
            const int ko = (kt + 3) * 32;
            const int bb = ((kt + 3) & 3) * 16384;
            glds16(aSrc[0] + ko, &lsm[bb + dstA[0]]);
            glds16(aSrc[1] + ko, &lsm[bb + dstA[1]]);
            glds16(bSrc[0] + ko, &lsm[bb + dstB[0]]);
            glds16(bSrc[1] + ko, &lsm[bb + dstB[1]]);
        }
        const uint16_t* ab = &lsm[b * 16384];
        short8 af[8], bf[4];
        #pragma unroll
        for (int g = 0; g < 8; ++g) af[g] = *(const short8*)(ab + offA[g]);
        #pragma unroll
        for (int n = 0; n < 4; ++n) bf[n] = *(const short8*)(ab + offB[n]);
        __builtin_amdgcn_s_setprio(1);
        #pragma unroll
        for (int mi = 0; mi < 8; ++mi)
            #pragma unroll
            for (int ni = 0; ni < 4; ++ni)
                acc[mi][ni] = __builtin_amdgcn_mfma_f32_16x16x32_bf16(
                    af[mi], bf[ni], acc[mi][ni], 0, 0, 0);
        __builtin_amdgcn_s_setprio(0);
        const int nin = NKT - 1 - kt;
        if (nin >= 3)      asm volatile("s_waitcnt vmcnt(8)" ::: "memory");
        else if (nin == 2) asm volatile("s_waitcnt vmcnt(4)" ::: "memory");
        else if (nin == 1) asm volatile("s_waitcnt vmcnt(0)" ::: "memory");
        __builtin_amdgcn_s_barrier();
        asm volatile("" ::: "memory");
    }

    // ---- epilogue: D mapping col = lane&15, row = (lane>>4)*4 + j [m89/m91] ----
    const float* bias = biasFull + (size_t)e * ncols;
    if (ATOMIC) {
        #pragma unroll
        for (int mi = 0; mi < 8; ++mi) {
            const int rbase = wr * 128 + mi * 16 + ks * 4;
            #pragma unroll
            for (int ni = 0; ni < 4; ++ni) {
                const int c = n0 + wc * 64 + ni * 16 + fr;
                const float bv = bias[c];
                #pragma unroll
                for (int j = 0; j < 4; ++j) {
                    const int rl = rbase + j;
                    if (row0 + rl < ce) {
                        float v = acc[mi][ni][j] + bv;
                        atomicAdd(&OutF[(size_t)lT[rl] * DMODEL + c], lW[rl] * v);
                    }
                }
            }
        }
    } else {
        for (int half = 0; half < 2; ++half) {
            __syncthreads();
            if (wr == half) {
                #pragma unroll
                for (int mi = 0; mi < 8; ++mi) {
                    #pragma unroll
                    for (int ni = 0; ni < 4; ++ni) {
                        const int cl = wc * 64 + ni * 16 + fr;
                        const float bv = bias[n0 + cl];
                        #pragma unroll
                        for (int j = 0; j < 4; ++j) {
                            float v = acc[mi][ni][j] + bv;
                            if (GELU) v = gelu_tanh(v);
                            const int rl2 = mi * 16 + ks * 4 + j;
                            lsm[rl2 * 264 + cl] = f2bf(v);
                        }
                    }
                }
            }
            __syncthreads();
            #pragma unroll
            for (int p = 0; p < 8; ++p) {
                const int r2 = p * 16 + (t >> 5);
                const int cg = (t & 31) * 8;
                short8 v = *(const short8*)&lsm[r2 * 264 + cg];
                *(short8*)&OutBf[((size_t)rbi * 256 + half * 128 + r2) * ncols + n0 + cg] = v;
            }
        }
    }
}

// ---------------- combine: out[t] = w0*y2[p0] + w1*y2[p1] (gather, no atomics) ----
__global__ __launch_bounds__(256) void combine_kernel(
    const uint16_t* __restrict__ y2,
    const int* __restrict__ tpos0, const int* __restrict__ tpos1,
    const float* __restrict__ tw0, const float* __restrict__ tw1,
    const int* __restrict__ ebase, float* __restrict__ out)
{
    const int wid = threadIdx.x >> 6, lane = threadIdx.x & 63;
    const int t = blockIdx.x * 4 + wid;
    const int p0 = tpos0[t], p1 = tpos1[t];
    const int e0 = p0 >> 15, s0 = p0 & 32767;
    const int e1 = p1 >> 15, s1 = p1 & 32767;
    const bool v0 = s0 < CAP, v1 = s1 < CAP;
    const float w0 = v0 ? tw0[t] : 0.0f;
    const float w1 = v1 ? tw1[t] : 0.0f;
    const uint16_t* r0p = y2 + ((size_t)ebase[e0] + (v0 ? s0 : 0)) * DMODEL;
    const uint16_t* r1p = y2 + ((size_t)ebase[e1] + (v1 ? s1 : 0)) * DMODEL;
    float* op = out + (size_t)t * DMODEL;
    #pragma unroll
    for (int half = 0; half < 2; ++half) {
        const int off = half * 512 + lane * 8;
        short8 a = *(const short8*)(r0p + off);
        short8 b = *(const short8*)(r1p + off);
        float4 o0, o1;
        o0.x = w0 * bf2f((uint16_t)a[0]) + w1 * bf2f((uint16_t)b[0]);
        o0.y = w0 * bf2f((uint16_t)a[1]) + w1 * bf2f((uint16_t)b[1]);
        o0.z = w0 * bf2f((uint16_t)a[2]) + w1 * bf2f((uint16_t)b[2]);
        o0.w = w0 * bf2f((uint16_t)a[3]) + w1 * bf2f((uint16_t)b[3]);
        o1.x = w0 * bf2f((uint16_t)a[4]) + w1 * bf2f((uint16_t)b[4]);
        o1.y = w0 * bf2f((uint16_t)a[5]) + w1 * bf2f((uint16_t)b[5]);
        o1.z = w0 * bf2f((uint16_t)a[6]) + w1 * bf2f((uint16_t)b[6]);
        o1.w = w0 * bf2f((uint16_t)a[7]) + w1 * bf2f((uint16_t)b[7]);
        *(float4*)(op + off)     = o0;
        *(float4*)(op + off + 4) = o1;
    }
}

// ---------------- load-loss finalize ----------------
__global__ void finalize_kernel(const float* __restrict__ loadAcc, float* __restrict__ out) {
    if (threadIdx.x == 0) {
        float m = 0.f;
        #pragma unroll
        for (int e = 0; e < 8; ++e) m += loadAcc[e];
        m *= 0.125f;
        float v = 0.f;
        #pragma unroll
        for (int e = 0; e < 8; ++e) { float d0 = loadAcc[e] - m; v += d0 * d0; }
        v *= (1.0f / 7.0f);   // ddof=1
        out[(size_t)N_TOK * DMODEL] = W_LOAD_C * v / (m * m);
    }
}

extern "C" void kernel_launch(void* const* d_in, const int* in_sizes, int n_in,
                              void* d_out, int out_size, void* d_ws, size_t ws_size,
                              hipStream_t stream) {
    const float* x       = (const float*)d_in[0];
    const float* noise   = (const float*)d_in[1];
    const float* gate_w  = (const float*)d_in[2];
    const float* noise_w = (const float*)d_in[3];
    const float* w1      = (const float*)d_in[4];
    const float* b1      = (const float*)d_in[5];
    const float* w2      = (const float*)d_in[6];
    const float* b2      = (const float*)d_in[7];
    float* out = (float*)d_out;
    char* ws = (char*)d_ws;

    int*      cnt     = (int*)(ws + 0);
    float*    loadAcc = (float*)(ws + 256);
    int*      ebase   = (int*)(ws + 512);
    int*      be      = (int*)(ws + 1024);
    int*      brow    = (int*)(ws + 2048);
    int*      rowlist = (int*)(ws + 4096);        // 256 KiB
    int*      tpos0   = (int*)(ws + 266240);      // 64 KiB
    int*      tpos1   = (int*)(ws + 331776);
    float*    tw0     = (float*)(ws + 397312);
    float*    tw1     = (float*)(ws + 462848);
    float*    slotw   = (float*)(ws + 528384);    // 256 KiB (fallback only)
    uint16_t* xb      = (uint16_t*)(ws + 790528); // 32 MiB
    uint16_t* w1t     = (uint16_t*)(ws + 34344960);  // 64 MiB
    uint16_t* w2t     = (uint16_t*)(ws + 101453824); // 64 MiB
    uint16_t* h       = (uint16_t*)(ws + 168562688); // 272 MiB (MAXB*256 x 4096)
    const size_t HOFF = 168562688ull;
    const size_t HSZ  = (size_t)MAXB * 256 * DFF * 2;      // 285,212,672
    uint16_t* y2      = (uint16_t*)(ws + HOFF + HSZ);      // 68 MiB packed y+b2
    const size_t Y2SZ = (size_t)MAXB * 256 * DMODEL * 2;
    const bool gatherPath = ws_size >= HOFF + HSZ + Y2SZ;  // ~500 MiB

    hipMemsetAsync(ws, 0, 4096, stream);

    gating_kernel<<<2048, 512, 0, stream>>>(x, noise, gate_w, noise_w,
                                            cnt, loadAcc, rowlist, slotw,
                                            tpos0, tpos1, tw0, tw1, xb);
    scan_kernel<<<1, 64, 0, stream>>>(cnt, be, brow, ebase);
    transpose_w_kernel<<<dim3(128, 32, 8), 256, 0, stream>>>(w1, w1t, 1024, 4096);
    transpose_w_kernel<<<dim3(32, 128, 8), 256, 0, stream>>>(w2, w2t, 4096, 1024);
    finalize_kernel<<<1, 64, 0, stream>>>(loadAcc, out);

    if (gatherPath) {
        gemm_kernel<1024, 1, 1, 0><<<dim3(16, MAXB), 512, 0, stream>>>(
            xb, w1t, rowlist, slotw, cnt, be, brow, b1, h, nullptr, DFF, 0);
        gemm_kernel<4096, 0, 0, 0><<<dim3(4, MAXB), 512, 0, stream>>>(
            h, w2t, rowlist, slotw, cnt, be, brow, b2, y2, nullptr, DMODEL, 0);
        combine_kernel<<<4096, 256, 0, stream>>>(y2, tpos0, tpos1, tw0, tw1,
                                                 ebase, out);
    } else {
        // fallback: atomic combine (chunked if h doesn't fit)
        hipMemsetAsync(d_out, 0, (size_t)out_size * sizeof(float), stream);
        size_t avail = (ws_size > HOFF) ? ws_size - HOFF : 0;
        int nch = 8, bpc = (MAXB + 7) / 8;
        for (int c = 1; c <= 8; c <<= 1) {
            int b = (MAXB + c - 1) / c;
            if ((size_t)b * 256 * DFF * 2 <= avail) { nch = c; bpc = b; break; }
        }
        for (int c = 0; c < nch; ++c) {
            int bo = c * bpc;
            if (bo >= MAXB) break;
            gemm_kernel<1024, 1, 1, 0><<<dim3(16, bpc), 512, 0, stream>>>(
                xb, w1t, rowlist, slotw, cnt, be, brow, b1, h, nullptr, DFF, bo);
            gemm_kernel<4096, 0, 0, 1><<<dim3(4, bpc), 512, 0, stream>>>(
                h, w2t, rowlist, slotw, cnt, be, brow, b2, nullptr, out, DMODEL, bo);
        }
    }
}

// Round 7
// 1027.819 us; speedup vs baseline: 1.9753x; 1.0396x over previous
//
#include <hip/hip_runtime.h>
#include <stdint.h>

#define N_TOK   16384
#define DMODEL  1024
#define NEXP    8
#define DFF     4096
#define CAP     8192
#define MAXB    136          // 32768/256 + 8 (per-expert 256-row padding)
#define W_LOAD_C 0.01f

typedef __attribute__((ext_vector_type(8))) short short8;
typedef __attribute__((ext_vector_type(4))) float f32x4;

__device__ __forceinline__ uint16_t f2bf(float f) {
    uint32_t u = __float_as_uint(f);
    uint32_t r = u + 0x7fffu + ((u >> 16) & 1u);
    return (uint16_t)(r >> 16);
}
__device__ __forceinline__ float bf2f(uint16_t u) {
    return __uint_as_float((uint32_t)u << 16);
}

__device__ __forceinline__ float gelu_tanh(float v) {
    float u = 0.7978845608028654f * (v + 0.044715f * v * v * v);
    float ex = __expf(2.0f * u);
    float th = 1.0f - 2.0f / (ex + 1.0f);
    return 0.5f * v * (1.0f + th);
}

__device__ __forceinline__ void glds16(const uint16_t* g, uint16_t* l) {
    __builtin_amdgcn_global_load_lds(
        (const __attribute__((address_space(1))) void*)g,
        (__attribute__((address_space(3))) void*)l, 16, 0, 0);
}

// ---------------- gating + routing + load-loss + fused x->bf16 ----------------
// Dot-product code kept bitwise-identical to the passing rounds.
__global__ __launch_bounds__(512) void gating_kernel(
    const float* __restrict__ x, const float* __restrict__ noise,
    const float* __restrict__ gate_w, const float* __restrict__ noise_w,
    int* __restrict__ cnt, float* __restrict__ loadAcc,
    int* __restrict__ rowlist, float* __restrict__ slotw,
    int* __restrict__ tpos0, int* __restrict__ tpos1,
    float* __restrict__ tw0, float* __restrict__ tw1,
    uint16_t* __restrict__ xb)
{
    __shared__ float lp[8][8];
    __shared__ int   se1[8], se2[8];
    __shared__ float sw1[8], sw2[8];

    const int lane = threadIdx.x & 63;
    const int wid  = threadIdx.x >> 6;
    const int t = blockIdx.x * 8 + wid;

    const float* xr = x + (size_t)t * DMODEL;
    uint16_t* xbr = xb + (size_t)t * DMODEL;
    float ag[8] = {0,0,0,0,0,0,0,0};
    float an[8] = {0,0,0,0,0,0,0,0};
    for (int j = 0; j < 16; ++j) {
        int idx = j * 64 + lane;
        float xv = xr[idx];
        xbr[idx] = f2bf(xv);
        const float4* gp  = (const float4*)(gate_w  + idx * 8);
        const float4* np_ = (const float4*)(noise_w + idx * 8);
        float4 g0 = gp[0], g1 = gp[1];
        float4 n0 = np_[0], n1 = np_[1];
        ag[0] += xv * g0.x; ag[1] += xv * g0.y; ag[2] += xv * g0.z; ag[3] += xv * g0.w;
        ag[4] += xv * g1.x; ag[5] += xv * g1.y; ag[6] += xv * g1.z; ag[7] += xv * g1.w;
        an[0] += xv * n0.x; an[1] += xv * n0.y; an[2] += xv * n0.z; an[3] += xv * n0.w;
        an[4] += xv * n1.x; an[5] += xv * n1.y; an[6] += xv * n1.z; an[7] += xv * n1.w;
    }
    #pragma unroll
    for (int m = 32; m >= 1; m >>= 1) {
        #pragma unroll
        for (int e = 0; e < 8; ++e) {
            ag[e] += __shfl_xor(ag[e], m, 64);
            an[e] += __shfl_xor(an[e], m, 64);
        }
    }
    float logit[8], sdv[8];
    #pragma unroll
    for (int e = 0; e < 8; ++e) {
        float a = an[e];
        float sp = (a > 20.0f) ? a : log1pf(expf(a));
        sdv[e] = sp;
        logit[e] = ag[e] + noise[(size_t)t * 8 + e] * sp;
    }
    float v1 = -1e30f, v2 = -1e30f, v3 = -1e30f; int i1 = 0, i2 = 0;
    #pragma unroll
    for (int e = 0; e < 8; ++e) {
        float v = logit[e];
        if (v > v1)      { v3 = v2; v2 = v1; i2 = i1; v1 = v; i1 = e; }
        else if (v > v2) { v3 = v2; v2 = v; i2 = e; }
        else if (v > v3) { v3 = v; }
    }
    if (lane < 8) {
        float kth = (lane == i1 || lane == i2) ? v3 : v2;
        float z = (logit[lane] - kth) / sdv[lane];
        lp[wid][lane] = 0.5f * erfcf(-z * 0.70710678118654752440f);
    }
    if (lane == 0) {
        float e2 = expf(v2 - v1);
        float inv = 1.0f / (1.0f + e2);
        se1[wid] = i1; se2[wid] = i2;
        sw1[wid] = inv; sw2[wid] = e2 * inv;
        tw0[t] = inv; tw1[t] = e2 * inv;
    }
    __syncthreads();
    if (threadIdx.x < 8) {
        int e = threadIdx.x;
        float s = 0.f;
        #pragma unroll
        for (int w = 0; w < 8; ++w) s += lp[w][e];
        atomicAdd(&loadAcc[e], s);
        int m = 0;
        #pragma unroll
        for (int w = 0; w < 8; ++w) m += (se1[w] == e) + (se2[w] == e);
        if (m > 0) {
            int b = atomicAdd(&cnt[e], m);
            #pragma unroll
            for (int w = 0; w < 8; ++w) {
                int tok = blockIdx.x * 8 + w;
                if (se1[w] == e) {
                    if (b < CAP) { rowlist[e * CAP + b] = tok; slotw[e * CAP + b] = sw1[w]; }
                    tpos0[tok] = e * 32768 + b;
                    b++;
                }
                if (se2[w] == e) {
                    if (b < CAP) { rowlist[e * CAP + b] = tok; slotw[e * CAP + b] = sw2[w]; }
                    tpos1[tok] = e * 32768 + b;
                    b++;
                }
            }
        }
    }
}

// ---------------- block map scan: expert/row per 256-row packed block ----------------
__global__ void scan_kernel(const int* __restrict__ cnt,
                            int* __restrict__ be, int* __restrict__ brow,
                            int* __restrict__ ebase)
{
    if (threadIdx.x == 0 && blockIdx.x == 0) {
        int idx = 0;
        for (int e = 0; e < NEXP; ++e) {
            int ce = cnt[e]; if (ce > CAP) ce = CAP;
            int nb = (ce + 255) >> 8;
            ebase[e] = idx * 256;
            for (int k = 0; k < nb; ++k) { be[idx] = e; brow[idx] = k * 256; idx++; }
        }
        for (; idx < MAXB; ++idx) { be[idx] = -1; brow[idx] = 0; }
    }
}

// ---------------- per-expert transpose f32 [R][C] -> bf16 [C][R] ----------------
__global__ __launch_bounds__(256) void transpose_w_kernel(
    const float* __restrict__ src, uint16_t* __restrict__ dst, int R, int Cc)
{
    __shared__ float tile[32][33];
    const float* s = src + (size_t)blockIdx.z * R * Cc;
    uint16_t*    d = dst + (size_t)blockIdx.z * R * Cc;
    int c0 = blockIdx.x * 32, r0 = blockIdx.y * 32;
    int tx = threadIdx.x & 31, ty = threadIdx.x >> 5;
    #pragma unroll
    for (int rr = ty; rr < 32; rr += 8)
        tile[rr][tx] = s[(size_t)(r0 + rr) * Cc + c0 + tx];
    __syncthreads();
    #pragma unroll
    for (int rr = ty; rr < 32; rr += 8)
        d[(size_t)(c0 + rr) * R + r0 + tx] = f2bf(tile[tx][rr]);
}

// ---------------- GEMM: 256x256 tile, BK=32, 8 waves ----------------
// 4-deep ring (T4 counted vmcnt, never 0) + m201-style per-phase interleave
// (T3: 2 phases/K-tile, 16-MFMA clusters, 2 raw barriers/phase, T5 setprio)
// + st_16x32 subtile LDS swizzle (T2, both-sides: pre-permuted global source
// granule + swizzled ds_read; one glds wave-instr fills one 1024B subtile).
// + T1 bijective XCD swizzle (m204).
template<int KTOT, int GATHER, int GELU, int ATOMIC>
__global__ __launch_bounds__(512, 1) void gemm_kernel(
    const uint16_t* __restrict__ Abase,
    const uint16_t* __restrict__ Bfull,
    const int*      __restrict__ rowlist,
    const float*    __restrict__ slotw,
    const int*      __restrict__ cnt,
    const int*      __restrict__ be,
    const int*      __restrict__ brow,
    const float*    __restrict__ biasFull,
    uint16_t*       __restrict__ OutBf,
    float*          __restrict__ OutF,
    int ncols, int bo)
{
    // 128 KiB: 4 ring slots x (A 16KB + B 16KB); slot = [tensor][16 subtiles
    // of 16rows x 32cols bf16 = 1024B each, contiguous]
    __shared__ uint16_t lsm[65536];
    __shared__ int   lT[256];
    __shared__ float lW[256];

    // bijective XCD swizzle (m204)
    const int nwg  = gridDim.x * gridDim.y;
    const int flat = blockIdx.y * gridDim.x + blockIdx.x;
    const int xcd = flat & 7, sid = flat >> 3;
    const int q = nwg >> 3, r8 = nwg & 7;
    const int f2 = (xcd < r8 ? xcd * (q + 1) : r8 * (q + 1) + (xcd - r8) * q) + sid;
    const int nx  = f2 % gridDim.x;
    const int rbi = f2 / gridDim.x;

    const int rb = rbi + bo;
    if (rb >= MAXB) return;
    const int e = be[rb];
    if (e < 0) return;
    const int row0 = brow[rb];
    int ce = cnt[e]; if (ce > CAP) ce = CAP;
    const int n0 = nx * 256;

    const int t    = threadIdx.x;
    const int lane = t & 63, wid = t >> 6;
    const int fr = lane & 15, ks = lane >> 4;
    const int wr = wid >> 2, wc = wid & 3;

    if (ATOMIC) {
        if (t < 256) {
            int rr = row0 + t;
            int rc = (rr < ce) ? rr : (ce - 1);
            lT[t] = rowlist[e * CAP + rc];
            lW[t] = (rr < ce) ? slotw[e * CAP + rr] : 0.0f;
        }
        __syncthreads();
    }

    // ---- staging: lane l fills bytes [l*16,l*16+16) of subtile st = i*8+wid.
    // Subtile = rows st*16..+15 x K 0..31 of the tile. Physical granule l&3
    // must hold LOGICAL granule (l&3)^((rsub>>3)<<1)  (st_16x32 inverse swz).
    const uint16_t* Bp = Bfull + (size_t)e * ncols * KTOT;
    const int rsub = lane >> 2;
    const int kof  = ((lane & 3) ^ (((lane >> 5) & 1) << 1)) * 8;
    const int rowT0 = wid * 16 + rsub;
    const int rowT1 = 128 + wid * 16 + rsub;
    size_t gr0, gr1;
    if (GATHER) {
        int r0c = row0 + rowT0; r0c = (r0c < ce) ? r0c : (ce - 1);
        int r1c = row0 + rowT1; r1c = (r1c < ce) ? r1c : (ce - 1);
        gr0 = (size_t)rowlist[e * CAP + r0c];
        gr1 = (size_t)rowlist[e * CAP + r1c];
    } else {
        gr0 = (size_t)rbi * 256 + rowT0;
        gr1 = (size_t)rbi * 256 + rowT1;
    }
    const uint16_t* srcA0 = Abase + gr0 * KTOT + kof;
    const uint16_t* srcA1 = Abase + gr1 * KTOT + kof;
    const uint16_t* srcB0 = Bp + (size_t)(n0 + rowT0) * KTOT + kof;
    const uint16_t* srcB1 = Bp + (size_t)(n0 + rowT1) * KTOT + kof;
    const int dA0 = wid * 1024 + lane * 16;         // LDS byte offsets (linear dest)
    const int dA1 = (8 + wid) * 1024 + lane * 16;
    const int dB0 = 16384 + dA0;
    const int dB1 = 16384 + dA1;

    // ---- ds_read byte offsets (swizzled): row r, granule ks -> physical
    // granule ks ^ ((r&8)?2:0); 2 lanes/bank per b128 beat -> conflict-free.
    const int sw = (ks * 16) ^ ((fr >> 3) << 5);
    int aOff[8], bOff[4];
    #pragma unroll
    for (int m = 0; m < 8; ++m) aOff[m] = (wr * 8 + m) * 1024 + fr * 64 + sw;
    #pragma unroll
    for (int n = 0; n < 4; ++n) bOff[n] = 16384 + (wc * 4 + n) * 1024 + fr * 64 + sw;

    f32x4 acc[8][4];
    #pragma unroll
    for (int a = 0; a < 8; ++a)
        #pragma unroll
        for (int b = 0; b < 4; ++b) acc[a][b] = (f32x4){0.f, 0.f, 0.f, 0.f};

    constexpr int NKT = KTOT / 32;
    char* lsb = (char*)lsm;

    // prologue: stage K-tiles 0,1,2 into slots 0,1,2; wait K-tile 0 only
    #pragma unroll
    for (int p = 0; p < 3; ++p) {
        char* db = lsb + p * 32768;
        glds16(srcA0 + p * 32, (uint16_t*)(db + dA0));
        glds16(srcA1 + p * 32, (uint16_t*)(db + dA1));
        glds16(srcB0 + p * 32, (uint16_t*)(db + dB0));
        glds16(srcB1 + p * 32, (uint16_t*)(db + dB1));
    }
    asm volatile("s_waitcnt vmcnt(8)" ::: "memory");
    __builtin_amdgcn_s_barrier();
    asm volatile("" ::: "memory");

    for (int kt = 0; kt < NKT; ++kt) {
        const char* sb = lsb + (kt & 3) * 32768;
        char* db = lsb + ((kt + 3) & 3) * 32768;
        const bool st3 = (kt + 3) < NKT;
        const int ko = (kt + 3) * 32;
        short8 bf[4], af[4];

        // ---- phase 0: stage A(t+3), read B-all + A mi0..3, 16 MFMA ----
        if (st3) {
            glds16(srcA0 + ko, (uint16_t*)(db + dA0));
            glds16(srcA1 + ko, (uint16_t*)(db + dA1));
        }
        #pragma unroll
        for (int n = 0; n < 4; ++n) bf[n] = *(const short8*)(sb + bOff[n]);
        #pragma unroll
        for (int m = 0; m < 4; ++m) af[m] = *(const short8*)(sb + aOff[m]);
        asm volatile("" ::: "memory");
        __builtin_amdgcn_s_barrier();
        __builtin_amdgcn_s_setprio(1);
        #pragma unroll
        for (int m = 0; m < 4; ++m)
            #pragma unroll
            for (int n = 0; n < 4; ++n)
                acc[m][n] = __builtin_amdgcn_mfma_f32_16x16x32_bf16(
                    af[m], bf[n], acc[m][n], 0, 0, 0);
        __builtin_amdgcn_s_setprio(0);
        asm volatile("" ::: "memory");
        __builtin_amdgcn_s_barrier();

        // ---- phase 1: stage B(t+3), read A mi4..7, 16 MFMA, counted vmcnt ----
        if (st3) {
            glds16(srcB0 + ko, (uint16_t*)(db + dB0));
            glds16(srcB1 + ko, (uint16_t*)(db + dB1));
        }
        #pragma unroll
        for (int m = 0; m < 4; ++m) af[m] = *(const short8*)(sb + aOff[4 + m]);
        asm volatile("" ::: "memory");
        __builtin_amdgcn_s_barrier();
        __builtin_amdgcn_s_setprio(1);
        #pragma unroll
        for (int m = 0; m < 4; ++m)
            #pragma unroll
            for (int n = 0; n < 4; ++n)
                acc[4 + m][n] = __builtin_amdgcn_mfma_f32_16x16x32_bf16(
                    af[m], bf[n], acc[4 + m][n], 0, 0, 0);
        __builtin_amdgcn_s_setprio(0);
        const int rem = NKT - 1 - kt;
        if (rem >= 3)      asm volatile("s_waitcnt vmcnt(8)" ::: "memory");
        else if (rem == 2) asm volatile("s_waitcnt vmcnt(4)" ::: "memory");
        else if (rem == 1) asm volatile("s_waitcnt vmcnt(0)" ::: "memory");
        asm volatile("" ::: "memory");
        __builtin_amdgcn_s_barrier();
        asm volatile("" ::: "memory");
    }

    // ---- epilogue: D mapping col = lane&15, row = (lane>>4)*4 + j [m89/m91] ----
    const float* bias = biasFull + (size_t)e * ncols;
    if (ATOMIC) {
        #pragma unroll
        for (int mi = 0; mi < 8; ++mi) {
            const int rbase = wr * 128 + mi * 16 + ks * 4;
            #pragma unroll
            for (int ni = 0; ni < 4; ++ni) {
                const int c = n0 + wc * 64 + ni * 16 + fr;
                const float bv = bias[c];
                #pragma unroll
                for (int j = 0; j < 4; ++j) {
                    const int rl = rbase + j;
                    if (row0 + rl < ce) {
                        float v = acc[mi][ni][j] + bv;
                        atomicAdd(&OutF[(size_t)lT[rl] * DMODEL + c], lW[rl] * v);
                    }
                }
            }
        }
    } else {
        // staged, coalesced stores; two 128-row halves through the LDS arena
        for (int half = 0; half < 2; ++half) {
            __syncthreads();
            if (wr == half) {
                #pragma unroll
                for (int mi = 0; mi < 8; ++mi) {
                    #pragma unroll
                    for (int ni = 0; ni < 4; ++ni) {
                        const int cl = wc * 64 + ni * 16 + fr;
                        const float bv = bias[n0 + cl];
                        #pragma unroll
                        for (int j = 0; j < 4; ++j) {
                            float v = acc[mi][ni][j] + bv;
                            if (GELU) v = gelu_tanh(v);
                            const int rl2 = mi * 16 + ks * 4 + j;
                            lsm[rl2 * 264 + cl] = f2bf(v);
                        }
                    }
                }
            }
            __syncthreads();
            #pragma unroll
            for (int p = 0; p < 8; ++p) {
                const int r2 = p * 16 + (t >> 5);
                const int cg = (t & 31) * 8;
                short8 v = *(const short8*)&lsm[r2 * 264 + cg];
                *(short8*)&OutBf[((size_t)rbi * 256 + half * 128 + r2) * ncols + n0 + cg] = v;
            }
        }
    }
}

// ---------------- combine: out[t] = w0*y2[p0] + w1*y2[p1] (gather, no atomics) ----
__global__ __launch_bounds__(256) void combine_kernel(
    const uint16_t* __restrict__ y2,
    const int* __restrict__ tpos0, const int* __restrict__ tpos1,
    const float* __restrict__ tw0, const float* __restrict__ tw1,
    const int* __restrict__ ebase, float* __restrict__ out)
{
    const int wid = threadIdx.x >> 6, lane = threadIdx.x & 63;
    const int t = blockIdx.x * 4 + wid;
    const int p0 = tpos0[t], p1 = tpos1[t];
    const int e0 = p0 >> 15, s0 = p0 & 32767;
    const int e1 = p1 >> 15, s1 = p1 & 32767;
    const bool v0 = s0 < CAP, v1 = s1 < CAP;
    const float w0 = v0 ? tw0[t] : 0.0f;
    const float w1 = v1 ? tw1[t] : 0.0f;
    const uint16_t* r0p = y2 + ((size_t)ebase[e0] + (v0 ? s0 : 0)) * DMODEL;
    const uint16_t* r1p = y2 + ((size_t)ebase[e1] + (v1 ? s1 : 0)) * DMODEL;
    float* op = out + (size_t)t * DMODEL;
    #pragma unroll
    for (int half = 0; half < 2; ++half) {
        const int off = half * 512 + lane * 8;
        short8 a = *(const short8*)(r0p + off);
        short8 b = *(const short8*)(r1p + off);
        float4 o0, o1;
        o0.x = w0 * bf2f((uint16_t)a[0]) + w1 * bf2f((uint16_t)b[0]);
        o0.y = w0 * bf2f((uint16_t)a[1]) + w1 * bf2f((uint16_t)b[1]);
        o0.z = w0 * bf2f((uint16_t)a[2]) + w1 * bf2f((uint16_t)b[2]);
        o0.w = w0 * bf2f((uint16_t)a[3]) + w1 * bf2f((uint16_t)b[3]);
        o1.x = w0 * bf2f((uint16_t)a[4]) + w1 * bf2f((uint16_t)b[4]);
        o1.y = w0 * bf2f((uint16_t)a[5]) + w1 * bf2f((uint16_t)b[5]);
        o1.z = w0 * bf2f((uint16_t)a[6]) + w1 * bf2f((uint16_t)b[6]);
        o1.w = w0 * bf2f((uint16_t)a[7]) + w1 * bf2f((uint16_t)b[7]);
        *(float4*)(op + off)     = o0;
        *(float4*)(op + off + 4) = o1;
    }
}

// ---------------- load-loss finalize ----------------
__global__ void finalize_kernel(const float* __restrict__ loadAcc, float* __restrict__ out) {
    if (threadIdx.x == 0) {
        float m = 0.f;
        #pragma unroll
        for (int e = 0; e < 8; ++e) m += loadAcc[e];
        m *= 0.125f;
        float v = 0.f;
        #pragma unroll
        for (int e = 0; e < 8; ++e) { float d0 = loadAcc[e] - m; v += d0 * d0; }
        v *= (1.0f / 7.0f);   // ddof=1
        out[(size_t)N_TOK * DMODEL] = W_LOAD_C * v / (m * m);
    }
}

extern "C" void kernel_launch(void* const* d_in, const int* in_sizes, int n_in,
                              void* d_out, int out_size, void* d_ws, size_t ws_size,
                              hipStream_t stream) {
    const float* x       = (const float*)d_in[0];
    const float* noise   = (const float*)d_in[1];
    const float* gate_w  = (const float*)d_in[2];
    const float* noise_w = (const float*)d_in[3];
    const float* w1      = (const float*)d_in[4];
    const float* b1      = (const float*)d_in[5];
    const float* w2      = (const float*)d_in[6];
    const float* b2      = (const float*)d_in[7];
    float* out = (float*)d_out;
    char* ws = (char*)d_ws;

    int*      cnt     = (int*)(ws + 0);
    float*    loadAcc = (float*)(ws + 256);
    int*      ebase   = (int*)(ws + 512);
    int*      be      = (int*)(ws + 1024);
    int*      brow    = (int*)(ws + 2048);
    int*      rowlist = (int*)(ws + 4096);        // 256 KiB
    int*      tpos0   = (int*)(ws + 266240);      // 64 KiB each
    int*      tpos1   = (int*)(ws + 331776);
    float*    tw0     = (float*)(ws + 397312);
    float*    tw1     = (float*)(ws + 462848);
    float*    slotw   = (float*)(ws + 528384);    // 256 KiB (fallback only)
    uint16_t* xb      = (uint16_t*)(ws + 790528); // 32 MiB
    uint16_t* w1t     = (uint16_t*)(ws + 34344960);  // 64 MiB
    uint16_t* w2t     = (uint16_t*)(ws + 101453824); // 64 MiB
    uint16_t* h       = (uint16_t*)(ws + 168562688); // 272 MiB
    const size_t HOFF = 168562688ull;
    const size_t HSZ  = (size_t)MAXB * 256 * DFF * 2;
    uint16_t* y2      = (uint16_t*)(ws + HOFF + HSZ);   // 68 MiB packed y+b2
    const size_t Y2SZ = (size_t)MAXB * 256 * DMODEL * 2;
    const bool gatherPath = ws_size >= HOFF + HSZ + Y2SZ;

    hipMemsetAsync(ws, 0, 4096, stream);

    gating_kernel<<<2048, 512, 0, stream>>>(x, noise, gate_w, noise_w,
                                            cnt, loadAcc, rowlist, slotw,
                                            tpos0, tpos1, tw0, tw1, xb);
    scan_kernel<<<1, 64, 0, stream>>>(cnt, be, brow, ebase);
    transpose_w_kernel<<<dim3(128, 32, 8), 256, 0, stream>>>(w1, w1t, 1024, 4096);
    transpose_w_kernel<<<dim3(32, 128, 8), 256, 0, stream>>>(w2, w2t, 4096, 1024);
    finalize_kernel<<<1, 64, 0, stream>>>(loadAcc, out);

    if (gatherPath) {
        gemm_kernel<1024, 1, 1, 0><<<dim3(16, MAXB), 512, 0, stream>>>(
            xb, w1t, rowlist, slotw, cnt, be, brow, b1, h, nullptr, DFF, 0);
        gemm_kernel<4096, 0, 0, 0><<<dim3(4, MAXB), 512, 0, stream>>>(
            h, w2t, rowlist, slotw, cnt, be, brow, b2, y2, nullptr, DMODEL, 0);
        combine_kernel<<<4096, 256, 0, stream>>>(y2, tpos0, tpos1, tw0, tw1,
                                                 ebase, out);
    } else {
        // fallback: atomic combine (chunked if h doesn't fit)
        hipMemsetAsync(d_out, 0, (size_t)out_size * sizeof(float), stream);
        size_t avail = (ws_size > HOFF) ? ws_size - HOFF : 0;
        int nch = 8, bpc = (MAXB + 7) / 8;
        for (int c = 1; c <= 8; c <<= 1) {
            int b = (MAXB + c - 1) / c;
            if ((size_t)b * 256 * DFF * 2 <= avail) { nch = c; bpc = b; break; }
        }
        for (int c = 0; c < nch; ++c) {
            int bo = c * bpc;
            if (bo >= MAXB) break;
            gemm_kernel<1024, 1, 1, 0><<<dim3(16, bpc), 512, 0, stream>>>(
                xb, w1t, rowlist, slotw, cnt, be, brow, b1, h, nullptr, DFF, bo);
            gemm_kernel<4096, 0, 0, 1><<<dim3(4, bpc), 512, 0, stream>>>(
                h, w2t, rowlist, slotw, cnt, be, brow, b2, nullptr, out, DMODEL, bo);
        }
    }
}

// Round 8
// 1021.854 us; speedup vs baseline: 1.9868x; 1.0058x over previous
//
#include <hip/hip_runtime.h>
#include <stdint.h>

#define N_TOK   16384
#define DMODEL  1024
#define NEXP    8
#define DFF     4096
#define CAP     8192
#define MAXB    136          // 32768/256 + 8 (per-expert 256-row padding)
#define W_LOAD_C 0.01f

typedef __attribute__((ext_vector_type(8))) short short8;
typedef __attribute__((ext_vector_type(4))) float f32x4;

__device__ __forceinline__ uint16_t f2bf(float f) {
    uint32_t u = __float_as_uint(f);
    uint32_t r = u + 0x7fffu + ((u >> 16) & 1u);
    return (uint16_t)(r >> 16);
}
__device__ __forceinline__ float bf2f(uint16_t u) {
    return __uint_as_float((uint32_t)u << 16);
}

__device__ __forceinline__ float gelu_tanh(float v) {
    float u = 0.7978845608028654f * (v + 0.044715f * v * v * v);
    float ex = __expf(2.0f * u);
    float th = 1.0f - 2.0f / (ex + 1.0f);
    return 0.5f * v * (1.0f + th);
}

__device__ __forceinline__ void glds16(const uint16_t* g, uint16_t* l) {
    __builtin_amdgcn_global_load_lds(
        (const __attribute__((address_space(1))) void*)g,
        (__attribute__((address_space(3))) void*)l, 16, 0, 0);
}

// ---------------- gating + routing + load-loss + fused x->bf16 ----------------
// Dot-product code kept bitwise-identical to the passing rounds.
__global__ __launch_bounds__(512) void gating_kernel(
    const float* __restrict__ x, const float* __restrict__ noise,
    const float* __restrict__ gate_w, const float* __restrict__ noise_w,
    int* __restrict__ cnt, float* __restrict__ loadAcc,
    int* __restrict__ rowlist, float* __restrict__ slotw,
    int* __restrict__ tpos0, int* __restrict__ tpos1,
    float* __restrict__ tw0, float* __restrict__ tw1,
    uint16_t* __restrict__ xb)
{
    __shared__ float lp[8][8];
    __shared__ int   se1[8], se2[8];
    __shared__ float sw1[8], sw2[8];

    const int lane = threadIdx.x & 63;
    const int wid  = threadIdx.x >> 6;
    const int t = blockIdx.x * 8 + wid;

    const float* xr = x + (size_t)t * DMODEL;
    uint16_t* xbr = xb + (size_t)t * DMODEL;
    float ag[8] = {0,0,0,0,0,0,0,0};
    float an[8] = {0,0,0,0,0,0,0,0};
    for (int j = 0; j < 16; ++j) {
        int idx = j * 64 + lane;
        float xv = xr[idx];
        xbr[idx] = f2bf(xv);
        const float4* gp  = (const float4*)(gate_w  + idx * 8);
        const float4* np_ = (const float4*)(noise_w + idx * 8);
        float4 g0 = gp[0], g1 = gp[1];
        float4 n0 = np_[0], n1 = np_[1];
        ag[0] += xv * g0.x; ag[1] += xv * g0.y; ag[2] += xv * g0.z; ag[3] += xv * g0.w;
        ag[4] += xv * g1.x; ag[5] += xv * g1.y; ag[6] += xv * g1.z; ag[7] += xv * g1.w;
        an[0] += xv * n0.x; an[1] += xv * n0.y; an[2] += xv * n0.z; an[3] += xv * n0.w;
        an[4] += xv * n1.x; an[5] += xv * n1.y; an[6] += xv * n1.z; an[7] += xv * n1.w;
    }
    #pragma unroll
    for (int m = 32; m >= 1; m >>= 1) {
        #pragma unroll
        for (int e = 0; e < 8; ++e) {
            ag[e] += __shfl_xor(ag[e], m, 64);
            an[e] += __shfl_xor(an[e], m, 64);
        }
    }
    float logit[8], sdv[8];
    #pragma unroll
    for (int e = 0; e < 8; ++e) {
        float a = an[e];
        float sp = (a > 20.0f) ? a : log1pf(expf(a));
        sdv[e] = sp;
        logit[e] = ag[e] + noise[(size_t)t * 8 + e] * sp;
    }
    float v1 = -1e30f, v2 = -1e30f, v3 = -1e30f; int i1 = 0, i2 = 0;
    #pragma unroll
    for (int e = 0; e < 8; ++e) {
        float v = logit[e];
        if (v > v1)      { v3 = v2; v2 = v1; i2 = i1; v1 = v; i1 = e; }
        else if (v > v2) { v3 = v2; v2 = v; i2 = e; }
        else if (v > v3) { v3 = v; }
    }
    if (lane < 8) {
        float kth = (lane == i1 || lane == i2) ? v3 : v2;
        float z = (logit[lane] - kth) / sdv[lane];
        lp[wid][lane] = 0.5f * erfcf(-z * 0.70710678118654752440f);
    }
    if (lane == 0) {
        float e2 = expf(v2 - v1);
        float inv = 1.0f / (1.0f + e2);
        se1[wid] = i1; se2[wid] = i2;
        sw1[wid] = inv; sw2[wid] = e2 * inv;
        tw0[t] = inv; tw1[t] = e2 * inv;
    }
    __syncthreads();
    if (threadIdx.x < 8) {
        int e = threadIdx.x;
        float s = 0.f;
        #pragma unroll
        for (int w = 0; w < 8; ++w) s += lp[w][e];
        atomicAdd(&loadAcc[e], s);
        int m = 0;
        #pragma unroll
        for (int w = 0; w < 8; ++w) m += (se1[w] == e) + (se2[w] == e);
        if (m > 0) {
            int b = atomicAdd(&cnt[e], m);
            #pragma unroll
            for (int w = 0; w < 8; ++w) {
                int tok = blockIdx.x * 8 + w;
                if (se1[w] == e) {
                    if (b < CAP) { rowlist[e * CAP + b] = tok; slotw[e * CAP + b] = sw1[w]; }
                    tpos0[tok] = e * 32768 + b;
                    b++;
                }
                if (se2[w] == e) {
                    if (b < CAP) { rowlist[e * CAP + b] = tok; slotw[e * CAP + b] = sw2[w]; }
                    tpos1[tok] = e * 32768 + b;
                    b++;
                }
            }
        }
    }
}

// ---------------- block map scan: expert/row per 256-row packed block ----------------
__global__ void scan_kernel(const int* __restrict__ cnt,
                            int* __restrict__ be, int* __restrict__ brow,
                            int* __restrict__ ebase)
{
    if (threadIdx.x == 0 && blockIdx.x == 0) {
        int idx = 0;
        for (int e = 0; e < NEXP; ++e) {
            int ce = cnt[e]; if (ce > CAP) ce = CAP;
            int nb = (ce + 255) >> 8;
            ebase[e] = idx * 256;
            for (int k = 0; k < nb; ++k) { be[idx] = e; brow[idx] = k * 256; idx++; }
        }
        for (; idx < MAXB; ++idx) { be[idx] = -1; brow[idx] = 0; }
    }
}

// ---------------- per-expert transpose f32 [R][C] -> bf16 [C][R] ----------------
__global__ __launch_bounds__(256) void transpose_w_kernel(
    const float* __restrict__ src, uint16_t* __restrict__ dst, int R, int Cc)
{
    __shared__ float tile[32][33];
    const float* s = src + (size_t)blockIdx.z * R * Cc;
    uint16_t*    d = dst + (size_t)blockIdx.z * R * Cc;
    int c0 = blockIdx.x * 32, r0 = blockIdx.y * 32;
    int tx = threadIdx.x & 31, ty = threadIdx.x >> 5;
    #pragma unroll
    for (int rr = ty; rr < 32; rr += 8)
        tile[rr][tx] = s[(size_t)(r0 + rr) * Cc + c0 + tx];
    __syncthreads();
    #pragma unroll
    for (int rr = ty; rr < 32; rr += 8)
        d[(size_t)(c0 + rr) * R + r0 + tx] = f2bf(tile[tx][rr]);
}

// ---------------- GEMM: 256x256 tile, BK=32, 8 waves ----------------
// 4-deep ring (T4 counted vmcnt, never 0) + per-phase interleave (T3) with
// **ONE barrier per phase (post-MFMA)** — the pre-MFMA barrier of r7 forced
// all-wave lockstep (LDS idle during MFMA, matrix idle during reads). With a
// single post-MFMA barrier, waves skew within a phase so one wave's ds_reads
// overlap another's MFMA (m114 mechanism); ordering is preserved: a staged
// buffer is 6 barriers from its readers, and the buffer being overwritten had
// its reads register-retired (lgkm data-dep before MFMA) before the barrier
// that precedes the overwriting glds issue.
// + st_16x32 subtile LDS swizzle (T2 both-sides) + T5 setprio + T1 XCD swizzle.
template<int KTOT, int GATHER, int GELU, int ATOMIC>
__global__ __launch_bounds__(512, 1) void gemm_kernel(
    const uint16_t* __restrict__ Abase,
    const uint16_t* __restrict__ Bfull,
    const int*      __restrict__ rowlist,
    const float*    __restrict__ slotw,
    const int*      __restrict__ cnt,
    const int*      __restrict__ be,
    const int*      __restrict__ brow,
    const float*    __restrict__ biasFull,
    uint16_t*       __restrict__ OutBf,
    float*          __restrict__ OutF,
    int ncols, int bo)
{
    // 128 KiB: 4 ring slots x (A 16KB + B 16KB); slot = [tensor][16 subtiles
    // of 16rows x 32cols bf16 = 1024B each, contiguous]
    __shared__ uint16_t lsm[65536];
    __shared__ int   lT[256];
    __shared__ float lW[256];

    // bijective XCD swizzle (m204)
    const int nwg  = gridDim.x * gridDim.y;
    const int flat = blockIdx.y * gridDim.x + blockIdx.x;
    const int xcd = flat & 7, sid = flat >> 3;
    const int q = nwg >> 3, r8 = nwg & 7;
    const int f2 = (xcd < r8 ? xcd * (q + 1) : r8 * (q + 1) + (xcd - r8) * q) + sid;
    const int nx  = f2 % gridDim.x;
    const int rbi = f2 / gridDim.x;

    const int rb = rbi + bo;
    if (rb >= MAXB) return;
    const int e = be[rb];
    if (e < 0) return;
    const int row0 = brow[rb];
    int ce = cnt[e]; if (ce > CAP) ce = CAP;
    const int n0 = nx * 256;

    const int t    = threadIdx.x;
    const int lane = t & 63, wid = t >> 6;
    const int fr = lane & 15, ks = lane >> 4;
    const int wr = wid >> 2, wc = wid & 3;

    if (ATOMIC) {
        if (t < 256) {
            int rr = row0 + t;
            int rc = (rr < ce) ? rr : (ce - 1);
            lT[t] = rowlist[e * CAP + rc];
            lW[t] = (rr < ce) ? slotw[e * CAP + rr] : 0.0f;
        }
        __syncthreads();
    }

    // ---- staging: lane l fills bytes [l*16,l*16+16) of subtile st = i*8+wid.
    // Subtile = rows st*16..+15 x K 0..31 of the tile. Physical granule l&3
    // must hold LOGICAL granule (l&3)^((rsub>>3)<<1)  (st_16x32 inverse swz).
    const uint16_t* Bp = Bfull + (size_t)e * ncols * KTOT;
    const int rsub = lane >> 2;
    const int kof  = ((lane & 3) ^ (((lane >> 5) & 1) << 1)) * 8;
    const int rowT0 = wid * 16 + rsub;
    const int rowT1 = 128 + wid * 16 + rsub;
    size_t gr0, gr1;
    if (GATHER) {
        int r0c = row0 + rowT0; r0c = (r0c < ce) ? r0c : (ce - 1);
        int r1c = row0 + rowT1; r1c = (r1c < ce) ? r1c : (ce - 1);
        gr0 = (size_t)rowlist[e * CAP + r0c];
        gr1 = (size_t)rowlist[e * CAP + r1c];
    } else {
        gr0 = (size_t)rbi * 256 + rowT0;
        gr1 = (size_t)rbi * 256 + rowT1;
    }
    const uint16_t* srcA0 = Abase + gr0 * KTOT + kof;
    const uint16_t* srcA1 = Abase + gr1 * KTOT + kof;
    const uint16_t* srcB0 = Bp + (size_t)(n0 + rowT0) * KTOT + kof;
    const uint16_t* srcB1 = Bp + (size_t)(n0 + rowT1) * KTOT + kof;
    const int dA0 = wid * 1024 + lane * 16;         // LDS byte offsets (linear dest)
    const int dA1 = (8 + wid) * 1024 + lane * 16;
    const int dB0 = 16384 + dA0;
    const int dB1 = 16384 + dA1;

    // ---- ds_read byte offsets (swizzled): row r, granule ks -> physical
    // granule ks ^ ((r&8)?2:0); 2 lanes/bank per b128 beat -> conflict-free.
    const int sw = (ks * 16) ^ ((fr >> 3) << 5);
    int aOff[8], bOff[4];
    #pragma unroll
    for (int m = 0; m < 8; ++m) aOff[m] = (wr * 8 + m) * 1024 + fr * 64 + sw;
    #pragma unroll
    for (int n = 0; n < 4; ++n) bOff[n] = 16384 + (wc * 4 + n) * 1024 + fr * 64 + sw;

    f32x4 acc[8][4];
    #pragma unroll
    for (int a = 0; a < 8; ++a)
        #pragma unroll
        for (int b = 0; b < 4; ++b) acc[a][b] = (f32x4){0.f, 0.f, 0.f, 0.f};

    constexpr int NKT = KTOT / 32;
    char* lsb = (char*)lsm;

    // prologue: stage K-tiles 0,1,2 into slots 0,1,2; wait K-tile 0 only
    #pragma unroll
    for (int p = 0; p < 3; ++p) {
        char* db = lsb + p * 32768;
        glds16(srcA0 + p * 32, (uint16_t*)(db + dA0));
        glds16(srcA1 + p * 32, (uint16_t*)(db + dA1));
        glds16(srcB0 + p * 32, (uint16_t*)(db + dB0));
        glds16(srcB1 + p * 32, (uint16_t*)(db + dB1));
    }
    asm volatile("s_waitcnt vmcnt(8)" ::: "memory");
    __builtin_amdgcn_s_barrier();
    asm volatile("" ::: "memory");

    for (int kt = 0; kt < NKT; ++kt) {
        const char* sb = lsb + (kt & 3) * 32768;
        char* db = lsb + ((kt + 3) & 3) * 32768;
        const bool st3 = (kt + 3) < NKT;
        const int ko = (kt + 3) * 32;
        short8 bf[4], af[4];

        // ---- phase 0: stage A(t+3), read B-all + A mi0..3, 16 MFMA, barrier ----
        if (st3) {
            glds16(srcA0 + ko, (uint16_t*)(db + dA0));
            glds16(srcA1 + ko, (uint16_t*)(db + dA1));
        }
        #pragma unroll
        for (int n = 0; n < 4; ++n) bf[n] = *(const short8*)(sb + bOff[n]);
        #pragma unroll
        for (int m = 0; m < 4; ++m) af[m] = *(const short8*)(sb + aOff[m]);
        __builtin_amdgcn_s_setprio(1);
        #pragma unroll
        for (int m = 0; m < 4; ++m)
            #pragma unroll
            for (int n = 0; n < 4; ++n)
                acc[m][n] = __builtin_amdgcn_mfma_f32_16x16x32_bf16(
                    af[m], bf[n], acc[m][n], 0, 0, 0);
        __builtin_amdgcn_s_setprio(0);
        asm volatile("" ::: "memory");
        __builtin_amdgcn_s_barrier();
        asm volatile("" ::: "memory");

        // ---- phase 1: stage B(t+3), read A mi4..7, 16 MFMA, vmcnt, barrier ----
        if (st3) {
            glds16(srcB0 + ko, (uint16_t*)(db + dB0));
            glds16(srcB1 + ko, (uint16_t*)(db + dB1));
        }
        #pragma unroll
        for (int m = 0; m < 4; ++m) af[m] = *(const short8*)(sb + aOff[4 + m]);
        __builtin_amdgcn_s_setprio(1);
        #pragma unroll
        for (int m = 0; m < 4; ++m)
            #pragma unroll
            for (int n = 0; n < 4; ++n)
                acc[4 + m][n] = __builtin_amdgcn_mfma_f32_16x16x32_bf16(
                    af[m], bf[n], acc[4 + m][n], 0, 0, 0);
        __builtin_amdgcn_s_setprio(0);
        const int rem = NKT - 1 - kt;
        if (rem >= 3)      asm volatile("s_waitcnt vmcnt(8)" ::: "memory");
        else if (rem == 2) asm volatile("s_waitcnt vmcnt(4)" ::: "memory");
        else if (rem == 1) asm volatile("s_waitcnt vmcnt(0)" ::: "memory");
        asm volatile("" ::: "memory");
        __builtin_amdgcn_s_barrier();
        asm volatile("" ::: "memory");
    }

    // ---- epilogue: D mapping col = lane&15, row = (lane>>4)*4 + j [m89/m91] ----
    const float* bias = biasFull + (size_t)e * ncols;
    if (ATOMIC) {
        #pragma unroll
        for (int mi = 0; mi < 8; ++mi) {
            const int rbase = wr * 128 + mi * 16 + ks * 4;
            #pragma unroll
            for (int ni = 0; ni < 4; ++ni) {
                const int c = n0 + wc * 64 + ni * 16 + fr;
                const float bv = bias[c];
                #pragma unroll
                for (int j = 0; j < 4; ++j) {
                    const int rl = rbase + j;
                    if (row0 + rl < ce) {
                        float v = acc[mi][ni][j] + bv;
                        atomicAdd(&OutF[(size_t)lT[rl] * DMODEL + c], lW[rl] * v);
                    }
                }
            }
        }
    } else {
        // staged, coalesced stores; two 128-row halves through the LDS arena
        for (int half = 0; half < 2; ++half) {
            __syncthreads();
            if (wr == half) {
                #pragma unroll
                for (int mi = 0; mi < 8; ++mi) {
                    #pragma unroll
                    for (int ni = 0; ni < 4; ++ni) {
                        const int cl = wc * 64 + ni * 16 + fr;
                        const float bv = bias[n0 + cl];
                        #pragma unroll
                        for (int j = 0; j < 4; ++j) {
                            float v = acc[mi][ni][j] + bv;
                            if (GELU) v = gelu_tanh(v);
                            const int rl2 = mi * 16 + ks * 4 + j;
                            lsm[rl2 * 264 + cl] = f2bf(v);
                        }
                    }
                }
            }
            __syncthreads();
            #pragma unroll
            for (int p = 0; p < 8; ++p) {
                const int r2 = p * 16 + (t >> 5);
                const int cg = (t & 31) * 8;
                short8 v = *(const short8*)&lsm[r2 * 264 + cg];
                *(short8*)&OutBf[((size_t)rbi * 256 + half * 128 + r2) * ncols + n0 + cg] = v;
            }
        }
    }
}

// ---------------- combine: out[t] = w0*y2[p0] + w1*y2[p1] (gather, no atomics) ----
__global__ __launch_bounds__(256) void combine_kernel(
    const uint16_t* __restrict__ y2,
    const int* __restrict__ tpos0, const int* __restrict__ tpos1,
    const float* __restrict__ tw0, const float* __restrict__ tw1,
    const int* __restrict__ ebase, float* __restrict__ out)
{
    const int wid = threadIdx.x >> 6, lane = threadIdx.x & 63;
    const int t = blockIdx.x * 4 + wid;
    const int p0 = tpos0[t], p1 = tpos1[t];
    const int e0 = p0 >> 15, s0 = p0 & 32767;
    const int e1 = p1 >> 15, s1 = p1 & 32767;
    const bool v0 = s0 < CAP, v1 = s1 < CAP;
    const float w0 = v0 ? tw0[t] : 0.0f;
    const float w1 = v1 ? tw1[t] : 0.0f;
    const uint16_t* r0p = y2 + ((size_t)ebase[e0] + (v0 ? s0 : 0)) * DMODEL;
    const uint16_t* r1p = y2 + ((size_t)ebase[e1] + (v1 ? s1 : 0)) * DMODEL;
    float* op = out + (size_t)t * DMODEL;
    #pragma unroll
    for (int half = 0; half < 2; ++half) {
        const int off = half * 512 + lane * 8;
        short8 a = *(const short8*)(r0p + off);
        short8 b = *(const short8*)(r1p + off);
        float4 o0, o1;
        o0.x = w0 * bf2f((uint16_t)a[0]) + w1 * bf2f((uint16_t)b[0]);
        o0.y = w0 * bf2f((uint16_t)a[1]) + w1 * bf2f((uint16_t)b[1]);
        o0.z = w0 * bf2f((uint16_t)a[2]) + w1 * bf2f((uint16_t)b[2]);
        o0.w = w0 * bf2f((uint16_t)a[3]) + w1 * bf2f((uint16_t)b[3]);
        o1.x = w0 * bf2f((uint16_t)a[4]) + w1 * bf2f((uint16_t)b[4]);
        o1.y = w0 * bf2f((uint16_t)a[5]) + w1 * bf2f((uint16_t)b[5]);
        o1.z = w0 * bf2f((uint16_t)a[6]) + w1 * bf2f((uint16_t)b[6]);
        o1.w = w0 * bf2f((uint16_t)a[7]) + w1 * bf2f((uint16_t)b[7]);
        *(float4*)(op + off)     = o0;
        *(float4*)(op + off + 4) = o1;
    }
}

// ---------------- load-loss finalize ----------------
__global__ void finalize_kernel(const float* __restrict__ loadAcc, float* __restrict__ out) {
    if (threadIdx.x == 0) {
        float m = 0.f;
        #pragma unroll
        for (int e = 0; e < 8; ++e) m += loadAcc[e];
        m *= 0.125f;
        float v = 0.f;
        #pragma unroll
        for (int e = 0; e < 8; ++e) { float d0 = loadAcc[e] - m; v += d0 * d0; }
        v *= (1.0f / 7.0f);   // ddof=1
        out[(size_t)N_TOK * DMODEL] = W_LOAD_C * v / (m * m);
    }
}

extern "C" void kernel_launch(void* const* d_in, const int* in_sizes, int n_in,
                              void* d_out, int out_size, void* d_ws, size_t ws_size,
                              hipStream_t stream) {
    const float* x       = (const float*)d_in[0];
    const float* noise   = (const float*)d_in[1];
    const float* gate_w  = (const float*)d_in[2];
    const float* noise_w = (const float*)d_in[3];
    const float* w1      = (const float*)d_in[4];
    const float* b1      = (const float*)d_in[5];
    const float* w2      = (const float*)d_in[6];
    const float* b2      = (const float*)d_in[7];
    float* out = (float*)d_out;
    char* ws = (char*)d_ws;

    int*      cnt     = (int*)(ws + 0);
    float*    loadAcc = (float*)(ws + 256);
    int*      ebase   = (int*)(ws + 512);
    int*      be      = (int*)(ws + 1024);
    int*      brow    = (int*)(ws + 2048);
    int*      rowlist = (int*)(ws + 4096);        // 256 KiB
    int*      tpos0   = (int*)(ws + 266240);      // 64 KiB each
    int*      tpos1   = (int*)(ws + 331776);
    float*    tw0     = (float*)(ws + 397312);
    float*    tw1     = (float*)(ws + 462848);
    float*    slotw   = (float*)(ws + 528384);    // 256 KiB (fallback only)
    uint16_t* xb      = (uint16_t*)(ws + 790528); // 32 MiB
    uint16_t* w1t     = (uint16_t*)(ws + 34344960);  // 64 MiB
    uint16_t* w2t     = (uint16_t*)(ws + 101453824); // 64 MiB
    uint16_t* h       = (uint16_t*)(ws + 168562688); // 272 MiB
    const size_t HOFF = 168562688ull;
    const size_t HSZ  = (size_t)MAXB * 256 * DFF * 2;
    uint16_t* y2      = (uint16_t*)(ws + HOFF + HSZ);   // 68 MiB packed y+b2
    const size_t Y2SZ = (size_t)MAXB * 256 * DMODEL * 2;
    const bool gatherPath = ws_size >= HOFF + HSZ + Y2SZ;

    hipMemsetAsync(ws, 0, 4096, stream);

    gating_kernel<<<2048, 512, 0, stream>>>(x, noise, gate_w, noise_w,
                                            cnt, loadAcc, rowlist, slotw,
                                            tpos0, tpos1, tw0, tw1, xb);
    scan_kernel<<<1, 64, 0, stream>>>(cnt, be, brow, ebase);
    transpose_w_kernel<<<dim3(128, 32, 8), 256, 0, stream>>>(w1, w1t, 1024, 4096);
    transpose_w_kernel<<<dim3(32, 128, 8), 256, 0, stream>>>(w2, w2t, 4096, 1024);
    finalize_kernel<<<1, 64, 0, stream>>>(loadAcc, out);

    if (gatherPath) {
        gemm_kernel<1024, 1, 1, 0><<<dim3(16, MAXB), 512, 0, stream>>>(
            xb, w1t, rowlist, slotw, cnt, be, brow, b1, h, nullptr, DFF, 0);
        gemm_kernel<4096, 0, 0, 0><<<dim3(4, MAXB), 512, 0, stream>>>(
            h, w2t, rowlist, slotw, cnt, be, brow, b2, y2, nullptr, DMODEL, 0);
        combine_kernel<<<4096, 256, 0, stream>>>(y2, tpos0, tpos1, tw0, tw1,
                                                 ebase, out);
    } else {
        // fallback: atomic combine (chunked if h doesn't fit)
        hipMemsetAsync(d_out, 0, (size_t)out_size * sizeof(float), stream);
        size_t avail = (ws_size > HOFF) ? ws_size - HOFF : 0;
        int nch = 8, bpc = (MAXB + 7) / 8;
        for (int c = 1; c <= 8; c <<= 1) {
            int b = (MAXB + c - 1) / c;
            if ((size_t)b * 256 * DFF * 2 <= avail) { nch = c; bpc = b; break; }
        }
        for (int c = 0; c < nch; ++c) {
            int bo = c * bpc;
            if (bo >= MAXB) break;
            gemm_kernel<1024, 1, 1, 0><<<dim3(16, bpc), 512, 0, stream>>>(
                xb, w1t, rowlist, slotw, cnt, be, brow, b1, h, nullptr, DFF, bo);
            gemm_kernel<4096, 0, 0, 1><<<dim3(4, bpc), 512, 0, stream>>>(
                h, w2t, rowlist, slotw, cnt, be, brow, b2, nullptr, out, DMODEL, bo);
        }
    }
}

// Round 9
// 1010.398 us; speedup vs baseline: 2.0094x; 1.0113x over previous
//
#include <hip/hip_runtime.h>
#include <stdint.h>

#define N_TOK   16384
#define DMODEL  1024
#define NEXP    8
#define DFF     4096
#define CAP     8192
#define MAXB    136          // 32768/256 + 8 (per-expert 256-row padding)
#define W_LOAD_C 0.01f

typedef __attribute__((ext_vector_type(8))) short short8;
typedef __attribute__((ext_vector_type(4))) float f32x4;

__device__ __forceinline__ uint16_t f2bf(float f) {
    uint32_t u = __float_as_uint(f);
    uint32_t r = u + 0x7fffu + ((u >> 16) & 1u);
    return (uint16_t)(r >> 16);
}
__device__ __forceinline__ float bf2f(uint16_t u) {
    return __uint_as_float((uint32_t)u << 16);
}

__device__ __forceinline__ float gelu_tanh(float v) {
    float u = 0.7978845608028654f * (v + 0.044715f * v * v * v);
    float ex = __expf(2.0f * u);
    float th = 1.0f - 2.0f / (ex + 1.0f);
    return 0.5f * v * (1.0f + th);
}

__device__ __forceinline__ void glds16(const uint16_t* g, uint16_t* l) {
    __builtin_amdgcn_global_load_lds(
        (const __attribute__((address_space(1))) void*)g,
        (__attribute__((address_space(3))) void*)l, 16, 0, 0);
}

// ---------------- gating + routing + load-loss + fused x->bf16 ----------------
// Dot-product code kept bitwise-identical to the passing rounds.
__global__ __launch_bounds__(512) void gating_kernel(
    const float* __restrict__ x, const float* __restrict__ noise,
    const float* __restrict__ gate_w, const float* __restrict__ noise_w,
    int* __restrict__ cnt, float* __restrict__ loadAcc,
    int* __restrict__ rowlist, float* __restrict__ slotw,
    int* __restrict__ tpos0, int* __restrict__ tpos1,
    float* __restrict__ tw0, float* __restrict__ tw1,
    uint16_t* __restrict__ xb)
{
    __shared__ float lp[8][8];
    __shared__ int   se1[8], se2[8];
    __shared__ float sw1[8], sw2[8];

    const int lane = threadIdx.x & 63;
    const int wid  = threadIdx.x >> 6;
    const int t = blockIdx.x * 8 + wid;

    const float* xr = x + (size_t)t * DMODEL;
    uint16_t* xbr = xb + (size_t)t * DMODEL;
    float ag[8] = {0,0,0,0,0,0,0,0};
    float an[8] = {0,0,0,0,0,0,0,0};
    for (int j = 0; j < 16; ++j) {
        int idx = j * 64 + lane;
        float xv = xr[idx];
        xbr[idx] = f2bf(xv);
        const float4* gp  = (const float4*)(gate_w  + idx * 8);
        const float4* np_ = (const float4*)(noise_w + idx * 8);
        float4 g0 = gp[0], g1 = gp[1];
        float4 n0 = np_[0], n1 = np_[1];
        ag[0] += xv * g0.x; ag[1] += xv * g0.y; ag[2] += xv * g0.z; ag[3] += xv * g0.w;
        ag[4] += xv * g1.x; ag[5] += xv * g1.y; ag[6] += xv * g1.z; ag[7] += xv * g1.w;
        an[0] += xv * n0.x; an[1] += xv * n0.y; an[2] += xv * n0.z; an[3] += xv * n0.w;
        an[4] += xv * n1.x; an[5] += xv * n1.y; an[6] += xv * n1.z; an[7] += xv * n1.w;
    }
    #pragma unroll
    for (int m = 32; m >= 1; m >>= 1) {
        #pragma unroll
        for (int e = 0; e < 8; ++e) {
            ag[e] += __shfl_xor(ag[e], m, 64);
            an[e] += __shfl_xor(an[e], m, 64);
        }
    }
    float logit[8], sdv[8];
    #pragma unroll
    for (int e = 0; e < 8; ++e) {
        float a = an[e];
        float sp = (a > 20.0f) ? a : log1pf(expf(a));
        sdv[e] = sp;
        logit[e] = ag[e] + noise[(size_t)t * 8 + e] * sp;
    }
    float v1 = -1e30f, v2 = -1e30f, v3 = -1e30f; int i1 = 0, i2 = 0;
    #pragma unroll
    for (int e = 0; e < 8; ++e) {
        float v = logit[e];
        if (v > v1)      { v3 = v2; v2 = v1; i2 = i1; v1 = v; i1 = e; }
        else if (v > v2) { v3 = v2; v2 = v; i2 = e; }
        else if (v > v3) { v3 = v; }
    }
    if (lane < 8) {
        float kth = (lane == i1 || lane == i2) ? v3 : v2;
        float z = (logit[lane] - kth) / sdv[lane];
        lp[wid][lane] = 0.5f * erfcf(-z * 0.70710678118654752440f);
    }
    if (lane == 0) {
        float e2 = expf(v2 - v1);
        float inv = 1.0f / (1.0f + e2);
        se1[wid] = i1; se2[wid] = i2;
        sw1[wid] = inv; sw2[wid] = e2 * inv;
        tw0[t] = inv; tw1[t] = e2 * inv;
    }
    __syncthreads();
    if (threadIdx.x < 8) {
        int e = threadIdx.x;
        float s = 0.f;
        #pragma unroll
        for (int w = 0; w < 8; ++w) s += lp[w][e];
        atomicAdd(&loadAcc[e], s);
        int m = 0;
        #pragma unroll
        for (int w = 0; w < 8; ++w) m += (se1[w] == e) + (se2[w] == e);
        if (m > 0) {
            int b = atomicAdd(&cnt[e], m);
            #pragma unroll
            for (int w = 0; w < 8; ++w) {
                int tok = blockIdx.x * 8 + w;
                if (se1[w] == e) {
                    if (b < CAP) { rowlist[e * CAP + b] = tok; slotw[e * CAP + b] = sw1[w]; }
                    tpos0[tok] = e * 32768 + b;
                    b++;
                }
                if (se2[w] == e) {
                    if (b < CAP) { rowlist[e * CAP + b] = tok; slotw[e * CAP + b] = sw2[w]; }
                    tpos1[tok] = e * 32768 + b;
                    b++;
                }
            }
        }
    }
}

// ---------------- block map scan: expert/row per 256-row packed block ----------------
__global__ void scan_kernel(const int* __restrict__ cnt,
                            int* __restrict__ be, int* __restrict__ brow,
                            int* __restrict__ ebase)
{
    if (threadIdx.x == 0 && blockIdx.x == 0) {
        int idx = 0;
        for (int e = 0; e < NEXP; ++e) {
            int ce = cnt[e]; if (ce > CAP) ce = CAP;
            int nb = (ce + 255) >> 8;
            ebase[e] = idx * 256;
            for (int k = 0; k < nb; ++k) { be[idx] = e; brow[idx] = k * 256; idx++; }
        }
        for (; idx < MAXB; ++idx) { be[idx] = -1; brow[idx] = 0; }
    }
}

// ---------------- per-expert transpose f32 [R][C] -> bf16 [C][R] ----------------
__global__ __launch_bounds__(256) void transpose_w_kernel(
    const float* __restrict__ src, uint16_t* __restrict__ dst, int R, int Cc)
{
    __shared__ float tile[32][33];
    const float* s = src + (size_t)blockIdx.z * R * Cc;
    uint16_t*    d = dst + (size_t)blockIdx.z * R * Cc;
    int c0 = blockIdx.x * 32, r0 = blockIdx.y * 32;
    int tx = threadIdx.x & 31, ty = threadIdx.x >> 5;
    #pragma unroll
    for (int rr = ty; rr < 32; rr += 8)
        tile[rr][tx] = s[(size_t)(r0 + rr) * Cc + c0 + tx];
    __syncthreads();
    #pragma unroll
    for (int rr = ty; rr < 32; rr += 8)
        d[(size_t)(c0 + rr) * R + r0 + tx] = f2bf(tile[tx][rr]);
}

// ---------------- GEMM: 256x256 tile, BK=32, 8 waves ----------------
// r9: register-level read pipelining. aflo (A m-frags 0-3 of tile kt) is read
// ONE PHASE EARLY (in ph1 of kt-1, after the counted-vmcnt barrier published
// slot kt). afhi is read in ph0 and consumed in ph1 (drains under ph0 MFMA).
// Only bf's 4 reads are same-phase (lgkmcnt(4), ~120cy exposed per K-tile).
// vmcnt ladder sits at ph0-end so the ph0-end BARRIER publishes tile kt+1
// across waves before ph1's cross-slot prefetch reads. sched_barrier(0) pins
// the prefetch reads above the MFMA clusters. 4-ring LDS, T2 swizzle, T5
// setprio, T1 XCD swizzle unchanged from r8.
template<int KTOT, int GATHER, int GELU, int ATOMIC>
__global__ __launch_bounds__(512, 1) void gemm_kernel(
    const uint16_t* __restrict__ Abase,
    const uint16_t* __restrict__ Bfull,
    const int*      __restrict__ rowlist,
    const float*    __restrict__ slotw,
    const int*      __restrict__ cnt,
    const int*      __restrict__ be,
    const int*      __restrict__ brow,
    const float*    __restrict__ biasFull,
    uint16_t*       __restrict__ OutBf,
    float*          __restrict__ OutF,
    int ncols, int bo)
{
    // 128 KiB: 4 ring slots x (A 16KB + B 16KB); slot = [tensor][16 subtiles
    // of 16rows x 32cols bf16 = 1024B each, contiguous]
    __shared__ uint16_t lsm[65536];
    __shared__ int   lT[256];
    __shared__ float lW[256];

    // bijective XCD swizzle (m204)
    const int nwg  = gridDim.x * gridDim.y;
    const int flat = blockIdx.y * gridDim.x + blockIdx.x;
    const int xcd = flat & 7, sid = flat >> 3;
    const int q = nwg >> 3, r8_ = nwg & 7;
    const int f2 = (xcd < r8_ ? xcd * (q + 1) : r8_ * (q + 1) + (xcd - r8_) * q) + sid;
    const int nx  = f2 % gridDim.x;
    const int rbi = f2 / gridDim.x;

    const int rb = rbi + bo;
    if (rb >= MAXB) return;
    const int e = be[rb];
    if (e < 0) return;
    const int row0 = brow[rb];
    int ce = cnt[e]; if (ce > CAP) ce = CAP;
    const int n0 = nx * 256;

    const int t    = threadIdx.x;
    const int lane = t & 63, wid = t >> 6;
    const int fr = lane & 15, ks = lane >> 4;
    const int wr = wid >> 2, wc = wid & 3;

    if (ATOMIC) {
        if (t < 256) {
            int rr = row0 + t;
            int rc = (rr < ce) ? rr : (ce - 1);
            lT[t] = rowlist[e * CAP + rc];
            lW[t] = (rr < ce) ? slotw[e * CAP + rr] : 0.0f;
        }
        __syncthreads();
    }

    // ---- staging: lane l fills bytes [l*16,l*16+16) of subtile st = i*8+wid.
    // st_16x32 inverse swizzle on the SOURCE granule.
    const uint16_t* Bp = Bfull + (size_t)e * ncols * KTOT;
    const int rsub = lane >> 2;
    const int kof  = ((lane & 3) ^ (((lane >> 5) & 1) << 1)) * 8;
    const int rowT0 = wid * 16 + rsub;
    const int rowT1 = 128 + wid * 16 + rsub;
    size_t gr0, gr1;
    if (GATHER) {
        int r0c = row0 + rowT0; r0c = (r0c < ce) ? r0c : (ce - 1);
        int r1c = row0 + rowT1; r1c = (r1c < ce) ? r1c : (ce - 1);
        gr0 = (size_t)rowlist[e * CAP + r0c];
        gr1 = (size_t)rowlist[e * CAP + r1c];
    } else {
        gr0 = (size_t)rbi * 256 + rowT0;
        gr1 = (size_t)rbi * 256 + rowT1;
    }
    const uint16_t* srcA0 = Abase + gr0 * KTOT + kof;
    const uint16_t* srcA1 = Abase + gr1 * KTOT + kof;
    const uint16_t* srcB0 = Bp + (size_t)(n0 + rowT0) * KTOT + kof;
    const uint16_t* srcB1 = Bp + (size_t)(n0 + rowT1) * KTOT + kof;
    const int dA0 = wid * 1024 + lane * 16;         // LDS byte offsets (linear dest)
    const int dA1 = (8 + wid) * 1024 + lane * 16;
    const int dB0 = 16384 + dA0;
    const int dB1 = 16384 + dA1;

    // ---- ds_read byte offsets (swizzled) ----
    const int sw = (ks * 16) ^ ((fr >> 3) << 5);
    int aOff[8], bOff[4];
    #pragma unroll
    for (int m = 0; m < 8; ++m) aOff[m] = (wr * 8 + m) * 1024 + fr * 64 + sw;
    #pragma unroll
    for (int n = 0; n < 4; ++n) bOff[n] = 16384 + (wc * 4 + n) * 1024 + fr * 64 + sw;

    f32x4 acc[8][4];
    #pragma unroll
    for (int a = 0; a < 8; ++a)
        #pragma unroll
        for (int b = 0; b < 4; ++b) acc[a][b] = (f32x4){0.f, 0.f, 0.f, 0.f};

    constexpr int NKT = KTOT / 32;   // 32 (GEMM1) / 128 (GEMM2): even
    char* lsb = (char*)lsm;

    // prologue: stage K-tiles 0,1,2 into slots 0,1,2; wait K-tile 0 only
    #pragma unroll
    for (int p = 0; p < 3; ++p) {
        char* db = lsb + p * 32768;
        glds16(srcA0 + p * 32, (uint16_t*)(db + dA0));
        glds16(srcA1 + p * 32, (uint16_t*)(db + dA1));
        glds16(srcB0 + p * 32, (uint16_t*)(db + dB0));
        glds16(srcB1 + p * 32, (uint16_t*)(db + dB1));
    }
    asm volatile("s_waitcnt vmcnt(8)" ::: "memory");
    __builtin_amdgcn_s_barrier();
    asm volatile("" ::: "memory");

    // pre-read aflo for tile 0 (slot 0)
    short8 afloP[4], afloQ[4];
    #pragma unroll
    for (int m = 0; m < 4; ++m) afloP[m] = *(const short8*)(lsb + aOff[m]);

#define K_STEP(KT, AFLO_C, AFLO_N)                                          \
  {                                                                         \
    const int kt_ = (KT);                                                   \
    const char* sb = lsb + (kt_ & 3) * 32768;                               \
    char* db = lsb + ((kt_ + 3) & 3) * 32768;                               \
    const bool st3 = (kt_ + 3) < NKT;                                       \
    const int ko = (kt_ + 3) * 32;                                          \
    short8 bf[4], afhi[4];                                                  \
    /* ---- phase 0: glds A(kt+3); read bf(kt)+afhi(kt); MFMA lo ---- */    \
    if (st3) {                                                              \
      glds16(srcA0 + ko, (uint16_t*)(db + dA0));                            \
      glds16(srcA1 + ko, (uint16_t*)(db + dA1));                            \
    }                                                                       \
    _Pragma("unroll")                                                       \
    for (int n = 0; n < 4; ++n) bf[n] = *(const short8*)(sb + bOff[n]);     \
    _Pragma("unroll")                                                       \
    for (int m = 0; m < 4; ++m) afhi[m] = *(const short8*)(sb + aOff[4+m]); \
    __builtin_amdgcn_sched_barrier(0);                                      \
    __builtin_amdgcn_s_setprio(1);                                          \
    _Pragma("unroll")                                                       \
    for (int m = 0; m < 4; ++m)                                             \
      _Pragma("unroll")                                                     \
      for (int n = 0; n < 4; ++n)                                           \
        acc[m][n] = __builtin_amdgcn_mfma_f32_16x16x32_bf16(                \
            AFLO_C[m], bf[n], acc[m][n], 0, 0, 0);                          \
    __builtin_amdgcn_s_setprio(0);                                          \
    __builtin_amdgcn_sched_barrier(0);                                      \
    {                                                                       \
      const int rem = NKT - 1 - kt_;                                        \
      if (rem >= 3)      asm volatile("s_waitcnt vmcnt(6)" ::: "memory");   \
      else if (rem == 2) asm volatile("s_waitcnt vmcnt(4)" ::: "memory");   \
      else if (rem == 1) asm volatile("s_waitcnt vmcnt(0)" ::: "memory");   \
    }                                                                       \
    __builtin_amdgcn_s_barrier();  /* publishes tile kt+1 to all waves */   \
    asm volatile("" ::: "memory");                                          \
    /* ---- phase 1: glds B(kt+3); prefetch aflo(kt+1); MFMA hi ---- */     \
    if (st3) {                                                              \
      glds16(srcB0 + ko, (uint16_t*)(db + dB0));                            \
      glds16(srcB1 + ko, (uint16_t*)(db + dB1));                            \
    }                                                                       \
    if (kt_ + 1 < NKT) {                                                    \
      const char* sn = lsb + ((kt_ + 1) & 3) * 32768;                       \
      _Pragma("unroll")                                                     \
      for (int m = 0; m < 4; ++m)                                           \
        AFLO_N[m] = *(const short8*)(sn + aOff[m]);                         \
    }                                                                       \
    __builtin_amdgcn_sched_barrier(0);                                      \
    __builtin_amdgcn_s_setprio(1);                                          \
    _Pragma("unroll")                                                       \
    for (int m = 0; m < 4; ++m)                                             \
      _Pragma("unroll")                                                     \
      for (int n = 0; n < 4; ++n)                                           \
        acc[4+m][n] = __builtin_amdgcn_mfma_f32_16x16x32_bf16(              \
            afhi[m], bf[n], acc[4+m][n], 0, 0, 0);                          \
    __builtin_amdgcn_s_setprio(0);                                          \
    __builtin_amdgcn_sched_barrier(0);                                      \
    asm volatile("" ::: "memory");                                          \
    __builtin_amdgcn_s_barrier();                                           \
    asm volatile("" ::: "memory");                                          \
  }

    for (int kt = 0; kt < NKT; kt += 2) {
        K_STEP(kt,     afloP, afloQ);
        K_STEP(kt + 1, afloQ, afloP);
    }
#undef K_STEP

    // ---- epilogue: D mapping col = lane&15, row = (lane>>4)*4 + j [m89/m91] ----
    const float* bias = biasFull + (size_t)e * ncols;
    if (ATOMIC) {
        #pragma unroll
        for (int mi = 0; mi < 8; ++mi) {
            const int rbase = wr * 128 + mi * 16 + ks * 4;
            #pragma unroll
            for (int ni = 0; ni < 4; ++ni) {
                const int c = n0 + wc * 64 + ni * 16 + fr;
                const float bv = bias[c];
                #pragma unroll
                for (int j = 0; j < 4; ++j) {
                    const int rl = rbase + j;
                    if (row0 + rl < ce) {
                        float v = acc[mi][ni][j] + bv;
                        atomicAdd(&OutF[(size_t)lT[rl] * DMODEL + c], lW[rl] * v);
                    }
                }
            }
        }
    } else {
        // staged, coalesced stores; two 128-row halves through the LDS arena
        for (int half = 0; half < 2; ++half) {
            __syncthreads();
            if (wr == half) {
                #pragma unroll
                for (int mi = 0; mi < 8; ++mi) {
                    #pragma unroll
                    for (int ni = 0; ni < 4; ++ni) {
                        const int cl = wc * 64 + ni * 16 + fr;
                        const float bv = bias[n0 + cl];
                        #pragma unroll
                        for (int j = 0; j < 4; ++j) {
                            float v = acc[mi][ni][j] + bv;
                            if (GELU) v = gelu_tanh(v);
                            const int rl2 = mi * 16 + ks * 4 + j;
                            lsm[rl2 * 264 + cl] = f2bf(v);
                        }
                    }
                }
            }
            __syncthreads();
            #pragma unroll
            for (int p = 0; p < 8; ++p) {
                const int r2 = p * 16 + (t >> 5);
                const int cg = (t & 31) * 8;
                short8 v = *(const short8*)&lsm[r2 * 264 + cg];
                *(short8*)&OutBf[((size_t)rbi * 256 + half * 128 + r2) * ncols + n0 + cg] = v;
            }
        }
    }
}

// ---------------- combine: out[t] = w0*y2[p0] + w1*y2[p1] (gather, no atomics) ----
__global__ __launch_bounds__(256) void combine_kernel(
    const uint16_t* __restrict__ y2,
    const int* __restrict__ tpos0, const int* __restrict__ tpos1,
    const float* __restrict__ tw0, const float* __restrict__ tw1,
    const int* __restrict__ ebase, float* __restrict__ out)
{
    const int wid = threadIdx.x >> 6, lane = threadIdx.x & 63;
    const int t = blockIdx.x * 4 + wid;
    const int p0 = tpos0[t], p1 = tpos1[t];
    const int e0 = p0 >> 15, s0 = p0 & 32767;
    const int e1 = p1 >> 15, s1 = p1 & 32767;
    const bool v0 = s0 < CAP, v1 = s1 < CAP;
    const float w0 = v0 ? tw0[t] : 0.0f;
    const float w1 = v1 ? tw1[t] : 0.0f;
    const uint16_t* r0p = y2 + ((size_t)ebase[e0] + (v0 ? s0 : 0)) * DMODEL;
    const uint16_t* r1p = y2 + ((size_t)ebase[e1] + (v1 ? s1 : 0)) * DMODEL;
    float* op = out + (size_t)t * DMODEL;
    #pragma unroll
    for (int half = 0; half < 2; ++half) {
        const int off = half * 512 + lane * 8;
        short8 a = *(const short8*)(r0p + off);
        short8 b = *(const short8*)(r1p + off);
        float4 o0, o1;
        o0.x = w0 * bf2f((uint16_t)a[0]) + w1 * bf2f((uint16_t)b[0]);
        o0.y = w0 * bf2f((uint16_t)a[1]) + w1 * bf2f((uint16_t)b[1]);
        o0.z = w0 * bf2f((uint16_t)a[2]) + w1 * bf2f((uint16_t)b[2]);
        o0.w = w0 * bf2f((uint16_t)a[3]) + w1 * bf2f((uint16_t)b[3]);
        o1.x = w0 * bf2f((uint16_t)a[4]) + w1 * bf2f((uint16_t)b[4]);
        o1.y = w0 * bf2f((uint16_t)a[5]) + w1 * bf2f((uint16_t)b[5]);
        o1.z = w0 * bf2f((uint16_t)a[6]) + w1 * bf2f((uint16_t)b[6]);
        o1.w = w0 * bf2f((uint16_t)a[7]) + w1 * bf2f((uint16_t)b[7]);
        *(float4*)(op + off)     = o0;
        *(float4*)(op + off + 4) = o1;
    }
}

// ---------------- load-loss finalize ----------------
__global__ void finalize_kernel(const float* __restrict__ loadAcc, float* __restrict__ out) {
    if (threadIdx.x == 0) {
        float m = 0.f;
        #pragma unroll
        for (int e = 0; e < 8; ++e) m += loadAcc[e];
        m *= 0.125f;
        float v = 0.f;
        #pragma unroll
        for (int e = 0; e < 8; ++e) { float d0 = loadAcc[e] - m; v += d0 * d0; }
        v *= (1.0f / 7.0f);   // ddof=1
        out[(size_t)N_TOK * DMODEL] = W_LOAD_C * v / (m * m);
    }
}

extern "C" void kernel_launch(void* const* d_in, const int* in_sizes, int n_in,
                              void* d_out, int out_size, void* d_ws, size_t ws_size,
                              hipStream_t stream) {
    const float* x       = (const float*)d_in[0];
    const float* noise   = (const float*)d_in[1];
    const float* gate_w  = (const float*)d_in[2];
    const float* noise_w = (const float*)d_in[3];
    const float* w1      = (const float*)d_in[4];
    const float* b1      = (const float*)d_in[5];
    const float* w2      = (const float*)d_in[6];
    const float* b2      = (const float*)d_in[7];
    float* out = (float*)d_out;
    char* ws = (char*)d_ws;

    int*      cnt     = (int*)(ws + 0);
    float*    loadAcc = (float*)(ws + 256);
    int*      ebase   = (int*)(ws + 512);
    int*      be      = (int*)(ws + 1024);
    int*      brow    = (int*)(ws + 2048);
    int*      rowlist = (int*)(ws + 4096);        // 256 KiB
    int*      tpos0   = (int*)(ws + 266240);      // 64 KiB each
    int*      tpos1   = (int*)(ws + 331776);
    float*    tw0     = (float*)(ws + 397312);
    float*    tw1     = (float*)(ws + 462848);
    float*    slotw   = (float*)(ws + 528384);    // 256 KiB (fallback only)
    uint16_t* xb      = (uint16_t*)(ws + 790528); // 32 MiB
    uint16_t* w1t     = (uint16_t*)(ws + 34344960);  // 64 MiB
    uint16_t* w2t     = (uint16_t*)(ws + 101453824); // 64 MiB
    uint16_t* h       = (uint16_t*)(ws + 168562688); // 272 MiB
    const size_t HOFF = 168562688ull;
    const size_t HSZ  = (size_t)MAXB * 256 * DFF * 2;
    uint16_t* y2      = (uint16_t*)(ws + HOFF + HSZ);   // 68 MiB packed y+b2
    const size_t Y2SZ = (size_t)MAXB * 256 * DMODEL * 2;
    const bool gatherPath = ws_size >= HOFF + HSZ + Y2SZ;

    hipMemsetAsync(ws, 0, 4096, stream);

    gating_kernel<<<2048, 512, 0, stream>>>(x, noise, gate_w, noise_w,
                                            cnt, loadAcc, rowlist, slotw,
                                            tpos0, tpos1, tw0, tw1, xb);
    scan_kernel<<<1, 64, 0, stream>>>(cnt, be, brow, ebase);
    transpose_w_kernel<<<dim3(128, 32, 8), 256, 0, stream>>>(w1, w1t, 1024, 4096);
    transpose_w_kernel<<<dim3(32, 128, 8), 256, 0, stream>>>(w2, w2t, 4096, 1024);
    finalize_kernel<<<1, 64, 0, stream>>>(loadAcc, out);

    if (gatherPath) {
        gemm_kernel<1024, 1, 1, 0><<<dim3(16, MAXB), 512, 0, stream>>>(
            xb, w1t, rowlist, slotw, cnt, be, brow, b1, h, nullptr, DFF, 0);
        gemm_kernel<4096, 0, 0, 0><<<dim3(4, MAXB), 512, 0, stream>>>(
            h, w2t, rowlist, slotw, cnt, be, brow, b2, y2, nullptr, DMODEL, 0);
        combine_kernel<<<4096, 256, 0, stream>>>(y2, tpos0, tpos1, tw0, tw1,
                                                 ebase, out);
    } else {
        // fallback: atomic combine (chunked if h doesn't fit)
        hipMemsetAsync(d_out, 0, (size_t)out_size * sizeof(float), stream);
        size_t avail = (ws_size > HOFF) ? ws_size - HOFF : 0;
        int nch = 8, bpc = (MAXB + 7) / 8;
        for (int c = 1; c <= 8; c <<= 1) {
            int b = (MAXB + c - 1) / c;
            if ((size_t)b * 256 * DFF * 2 <= avail) { nch = c; bpc = b; break; }
        }
        for (int c = 0; c < nch; ++c) {
            int bo = c * bpc;
            if (bo >= MAXB) break;
            gemm_kernel<1024, 1, 1, 0><<<dim3(16, bpc), 512, 0, stream>>>(
                xb, w1t, rowlist, slotw, cnt, be, brow, b1, h, nullptr, DFF, bo);
            gemm_kernel<4096, 0, 0, 1><<<dim3(4, bpc), 512, 0, stream>>>(
                h, w2t, rowlist, slotw, cnt, be, brow, b2, nullptr, out, DMODEL, bo);
        }
    }
}